// Round 6
// baseline (271.055 us; speedup 1.0000x reference)
//
#include <hip/hip_runtime.h>

#define RANK 128
#define LN_EPS 1e-5f

// CSR-build geometry (tuned for M=50000, nE=640000)
#define NCH 4
#define CHUNK 12800            // NCH*CHUNK = 51200 >= M ; LDS = 50 KB
#define BINS (NCH * CHUNK)
#define ECH 64                 // edge chunks
#define BT 1024                // threads per CSR-build block

using short8 = __attribute__((ext_vector_type(8))) short;
using v4f    = __attribute__((ext_vector_type(4))) float;

__device__ inline unsigned short f2bf(float f) {
    unsigned u = __float_as_uint(f);
    unsigned r = (u + 0x7FFF + ((u >> 16) & 1)) >> 16;   // RNE
    return (unsigned short)r;
}
__device__ inline float bf2f(unsigned short h) {
    return __uint_as_float(((unsigned)h) << 16);
}

// ---------------- partial histograms (no global atomics) ----------------
__global__ __launch_bounds__(BT) void hist_part(const int* __restrict__ src,
                                                const int* __restrict__ dst,
                                                int* __restrict__ pdst,
                                                int* __restrict__ psrc, int nE) {
    __shared__ int h[CHUNK];
    int c = blockIdx.x, n = blockIdx.y, z = blockIdx.z;
    const int* arr = z ? src : dst;
    int* pout = z ? psrc : pdst;
    int base = n * CHUNK;
    for (int i = threadIdx.x; i < CHUNK; i += BT) h[i] = 0;
    __syncthreads();
    int epc = (nE + ECH - 1) / ECH;
    int e0 = c * epc, e1 = min(e0 + epc, nE);
    for (int e = e0 + (int)threadIdx.x; e < e1; e += BT) {
        int v = arr[e] - base;
        if ((unsigned)v < (unsigned)CHUNK) atomicAdd(&h[v], 1);
    }
    __syncthreads();
    int* o = pout + (size_t)c * BINS + base;
    for (int i = threadIdx.x; i < CHUNK; i += BT) o[i] = h[i];
}

// ---------------- reduce partials -> counts + rsqrt normalizers ----------------
__global__ void reduce_part(const int* __restrict__ pdst, const int* __restrict__ psrc,
                            int* __restrict__ counts, float* __restrict__ invin,
                            float* __restrict__ invout, int M) {
    int b = blockIdx.x * blockDim.x + threadIdx.x;
    if (b >= M) return;
    int cd = 0, cs = 0;
#pragma unroll 8
    for (int c = 0; c < ECH; c++) {
        cd += pdst[(size_t)c * BINS + b];
        cs += psrc[(size_t)c * BINS + b];
    }
    counts[b] = cd;
    invin[b]  = rsqrtf(fmaxf((float)cd, 1.0f));
    invout[b] = rsqrtf(fmaxf((float)cs, 1.0f));
}

// ---------------- prefix scan (3-phase) -> inclusive ends ----------------
__global__ __launch_bounds__(256) void scan1_kernel(const int* __restrict__ counts,
                                                    int* __restrict__ ends,
                                                    int* __restrict__ bsums, int n) {
    __shared__ int tmp[256];
    int tid = threadIdx.x;
    int gid = blockIdx.x * 256 + tid;
    int v = (gid < n) ? counts[gid] : 0;
    tmp[tid] = v;
    __syncthreads();
    for (int off = 1; off < 256; off <<= 1) {
        int t = (tid >= off) ? tmp[tid - off] : 0;
        __syncthreads();
        tmp[tid] += t;
        __syncthreads();
    }
    if (gid < n) ends[gid] = tmp[tid];
    if (tid == 255) bsums[blockIdx.x] = tmp[255];
}

__global__ __launch_bounds__(256) void scan2_kernel(int* __restrict__ bsums, int nb) {
    __shared__ int tmp[256];
    int tid = threadIdx.x;
    int v = (tid < nb) ? bsums[tid] : 0;
    tmp[tid] = v;
    __syncthreads();
    for (int off = 1; off < 256; off <<= 1) {
        int t = (tid >= off) ? tmp[tid - off] : 0;
        __syncthreads();
        tmp[tid] += t;
        __syncthreads();
    }
    if (tid < nb) bsums[tid] = tmp[tid] - v;   // exclusive
}

__global__ __launch_bounds__(256) void scan3_kernel(int* __restrict__ ends,
                                                    const int* __restrict__ bsums, int n) {
    int gid = blockIdx.x * 256 + threadIdx.x;
    if (gid < n) ends[gid] += bsums[blockIdx.x];   // inclusive global ends
}

// ---------------- per-(chunk,bin) start offsets, in-place on pdst ----------------
__global__ void offs_kernel(int* __restrict__ pdst, const int* __restrict__ ends,
                            const int* __restrict__ counts, int M) {
    int b = blockIdx.x * blockDim.x + threadIdx.x;
    if (b >= M) return;
    int run = ends[b] - counts[b];
#pragma unroll 8
    for (int c = 0; c < ECH; c++) {
        size_t idx = (size_t)c * BINS + b;
        int t = pdst[idx];
        pdst[idx] = run;
        run += t;
    }
}

// ---------------- CSR fill via LDS cursors (no global atomics) ----------------
__global__ __launch_bounds__(BT) void fill_sorted(const int* __restrict__ src,
                                                  const int* __restrict__ dst,
                                                  const int* __restrict__ pdst,
                                                  int* __restrict__ csr_src, int nE) {
    __shared__ int cur[CHUNK];
    int c = blockIdx.x, n = blockIdx.y;
    int base = n * CHUNK;
    const int* o = pdst + (size_t)c * BINS + base;
    for (int i = threadIdx.x; i < CHUNK; i += BT) cur[i] = o[i];
    __syncthreads();
    int epc = (nE + ECH - 1) / ECH;
    int e0 = c * epc, e1 = min(e0 + epc, nE);
    for (int e = e0 + (int)threadIdx.x; e < e1; e += BT) {
        int d = dst[e] - base;
        if ((unsigned)d < (unsigned)CHUNK) {
            int pos = atomicAdd(&cur[d], 1);   // LDS atomic
            csr_src[pos] = src[e];
        }
    }
}

// ---------------- features fp32 -> bf16 ----------------
__global__ void convert_kernel(const float* __restrict__ X, unsigned* __restrict__ Xb, int n2) {
    int i = blockIdx.x * blockDim.x + threadIdx.x;
    if (i < n2) {
        float2 v = ((const float2*)X)[i];
        Xb[i] = (unsigned)f2bf(v.x) | ((unsigned)f2bf(v.y) << 16);
    }
}

// ---------------- W repack to MFMA B-fragment order ----------------
__global__ void repack_kernel(const float* __restrict__ Ws, short* __restrict__ Wt) {
    int l = blockIdx.x >> 3;
    int s = (blockIdx.x & 7) * 256 + threadIdx.x;
    int lane = s & 63, ct = (s >> 6) & 7, k0 = s >> 9;
    int m = lane & 15, quad = lane >> 4;
    const float* W = Ws + (size_t)l * RANK * RANK;
    short* o = Wt + (size_t)l * 16384 + (size_t)s * 8;
#pragma unroll
    for (int j = 0; j < 8; j++)
        o[j] = (short)f2bf(W[(k0 * 32 + quad * 8 + j) * RANK + ct * 16 + m]);
}

// ---------------- bf16 MFMA GEMM: H = (X @ W) * invout[row] ----------------
__global__ __launch_bounds__(256) void gemm_mfma(const short* __restrict__ Xb,
                                                 const short* __restrict__ Wt,
                                                 const float* __restrict__ invout,
                                                 unsigned short* __restrict__ H, int M) {
    int wave = threadIdx.x >> 6, lane = threadIdx.x & 63;
    int rowBase = blockIdx.x * 64 + wave * 16;
    int m = lane & 15, quad = lane >> 4;

    const short* arow = Xb + (size_t)(rowBase + m) * RANK + quad * 8;

    v4f acc[8];
#pragma unroll
    for (int ct = 0; ct < 8; ct++) acc[ct] = (v4f){0.f, 0.f, 0.f, 0.f};

#pragma unroll
    for (int k0 = 0; k0 < 4; k0++) {
        short8 a = *(const short8*)(arow + k0 * 32);
#pragma unroll
        for (int ct = 0; ct < 8; ct++) {
            short8 b = *(const short8*)(Wt + (size_t)((k0 * 8 + ct) * 64 + lane) * 8);
            acc[ct] = __builtin_amdgcn_mfma_f32_16x16x32_bf16(a, b, acc[ct], 0, 0, 0);
        }
    }

    float s[4];
    int rows[4];
#pragma unroll
    for (int r = 0; r < 4; r++) {
        rows[r] = rowBase + quad * 4 + r;
        s[r] = (rows[r] < M) ? invout[rows[r]] : 0.f;
    }
#pragma unroll
    for (int ct = 0; ct < 8; ct++) {
        int col = ct * 16 + m;
#pragma unroll
        for (int r = 0; r < 4; r++) {
            if (rows[r] < M)
                H[(size_t)rows[r] * RANK + col] = f2bf(acc[ct][r] * s[r]);
        }
    }
}

// ---------------- fused CSR gather + scale + bias + LN + ReLU (bf16 io) ----------------
// one wave per node; lane = seg*16 + m: seg picks 1 of 4 edges per group,
// m picks 16 B (8 cols) of the 256 B row -> one dwordx4 load covers 4 edges/wave
__global__ __launch_bounds__(256) void gatherln_kernel(const unsigned* __restrict__ H,
                                                       const int* __restrict__ ends,
                                                       const int* __restrict__ csr_src,
                                                       const float* __restrict__ invin,
                                                       const float* __restrict__ bias,
                                                       const float* __restrict__ gamma,
                                                       const float* __restrict__ beta,
                                                       unsigned* __restrict__ out, int M) {
    int wid = threadIdx.x >> 6;
    int lane = threadIdx.x & 63;
    int node = blockIdx.x * 4 + wid;
    if (node >= M) return;
    int seg = lane >> 4;       // 0..3
    int m   = lane & 15;       // 0..15

    int end = ends[node];
    int e   = (node == 0) ? 0 : ends[node - 1];

    float ax[8];
#pragma unroll
    for (int k = 0; k < 8; k++) ax[k] = 0.f;

    while (e < end) {
        int rem = end - e;
        int myi = 0;
        if (lane < rem) myi = csr_src[e + lane];
        int n = min(rem, 64);
        int t = 0;
        // 16 edges (4 groups of 4) per iteration: 4 independent dwordx4 loads
        for (; t + 16 <= n; t += 16) {
            uint4 u[4];
#pragma unroll
            for (int gi = 0; gi < 4; gi++) {
                int idx = __shfl(myi, t + gi * 4 + seg);
                u[gi] = *(const uint4*)(H + (size_t)idx * 64 + m * 4);
            }
#pragma unroll
            for (int gi = 0; gi < 4; gi++) {
                ax[0] += __uint_as_float(u[gi].x << 16);
                ax[1] += __uint_as_float(u[gi].x & 0xFFFF0000u);
                ax[2] += __uint_as_float(u[gi].y << 16);
                ax[3] += __uint_as_float(u[gi].y & 0xFFFF0000u);
                ax[4] += __uint_as_float(u[gi].z << 16);
                ax[5] += __uint_as_float(u[gi].z & 0xFFFF0000u);
                ax[6] += __uint_as_float(u[gi].w << 16);
                ax[7] += __uint_as_float(u[gi].w & 0xFFFF0000u);
            }
        }
        for (; t < n; t += 4) {
            bool act = (t + seg) < n;
            int idx = __shfl(myi, (t + seg) & 63);
            if (act) {
                uint4 u = *(const uint4*)(H + (size_t)idx * 64 + m * 4);
                ax[0] += __uint_as_float(u.x << 16);
                ax[1] += __uint_as_float(u.x & 0xFFFF0000u);
                ax[2] += __uint_as_float(u.y << 16);
                ax[3] += __uint_as_float(u.y & 0xFFFF0000u);
                ax[4] += __uint_as_float(u.z << 16);
                ax[5] += __uint_as_float(u.z & 0xFFFF0000u);
                ax[6] += __uint_as_float(u.w << 16);
                ax[7] += __uint_as_float(u.w & 0xFFFF0000u);
            }
        }
        e += n;
    }

    // combine the 4 edge-segments: lanes with equal m sum across seg
#pragma unroll
    for (int k = 0; k < 8; k++) {
        ax[k] += __shfl_xor(ax[k], 16);
        ax[k] += __shfl_xor(ax[k], 32);
    }
    // now every lane holds full column sums for cols m*8 .. m*8+7

    float s = invin[node];
    float4 b0 = ((const float4*)bias)[m * 2];
    float4 b1 = ((const float4*)bias)[m * 2 + 1];
    float x[8];
    x[0] = ax[0] * s + b0.x; x[1] = ax[1] * s + b0.y;
    x[2] = ax[2] * s + b0.z; x[3] = ax[3] * s + b0.w;
    x[4] = ax[4] * s + b1.x; x[5] = ax[5] * s + b1.y;
    x[6] = ax[6] * s + b1.z; x[7] = ax[7] * s + b1.w;

    float sum = 0.f, sq = 0.f;
#pragma unroll
    for (int k = 0; k < 8; k++) { sum += x[k]; sq += x[k] * x[k]; }
#pragma unroll
    for (int off = 1; off < 16; off <<= 1) {
        sum += __shfl_xor(sum, off);
        sq  += __shfl_xor(sq, off);
    }
    float mu = sum * (1.0f / RANK);
    float var = sq * (1.0f / RANK) - mu * mu;
    float r = rsqrtf(var + LN_EPS);

    float4 g0 = ((const float4*)gamma)[m * 2];
    float4 g1 = ((const float4*)gamma)[m * 2 + 1];
    float4 p0 = ((const float4*)beta)[m * 2];
    float4 p1 = ((const float4*)beta)[m * 2 + 1];
    float y[8];
    y[0] = fmaxf((x[0] - mu) * r * g0.x + p0.x, 0.f);
    y[1] = fmaxf((x[1] - mu) * r * g0.y + p0.y, 0.f);
    y[2] = fmaxf((x[2] - mu) * r * g0.z + p0.z, 0.f);
    y[3] = fmaxf((x[3] - mu) * r * g0.w + p0.w, 0.f);
    y[4] = fmaxf((x[4] - mu) * r * g1.x + p1.x, 0.f);
    y[5] = fmaxf((x[5] - mu) * r * g1.y + p1.y, 0.f);
    y[6] = fmaxf((x[6] - mu) * r * g1.z + p1.z, 0.f);
    y[7] = fmaxf((x[7] - mu) * r * g1.w + p1.w, 0.f);

    if (seg == 0) {
        uint4 o;
        o.x = (unsigned)f2bf(y[0]) | ((unsigned)f2bf(y[1]) << 16);
        o.y = (unsigned)f2bf(y[2]) | ((unsigned)f2bf(y[3]) << 16);
        o.z = (unsigned)f2bf(y[4]) | ((unsigned)f2bf(y[5]) << 16);
        o.w = (unsigned)f2bf(y[6]) | ((unsigned)f2bf(y[7]) << 16);
        *(uint4*)(out + (size_t)node * 64 + m * 4) = o;
    }
}

// ---------------- final gather: bf16 feats -> fp32 out ----------------
__global__ void gather_kernel(const unsigned short* __restrict__ feats,
                              const int* __restrict__ bnn,
                              float* __restrict__ out, int nG) {
    int g = blockIdx.x;
    int c = threadIdx.x;
    int idx = 0;
    for (int i = 0; i < g; i++) idx += bnn[i];
    out[(size_t)g * RANK + c] = bf2f(feats[(size_t)idx * RANK + c]);
}

extern "C" void kernel_launch(void* const* d_in, const int* in_sizes, int n_in,
                              void* d_out, int out_size, void* d_ws, size_t ws_size,
                              hipStream_t stream) {
    const float* features = (const float*)d_in[0];
    const int* src = (const int*)d_in[1];
    const int* dst = (const int*)d_in[2];
    const int* bnn = (const int*)d_in[3];
    const float* Ws = (const float*)d_in[4];
    const float* bs = (const float*)d_in[5];
    const float* gammas = (const float*)d_in[6];
    const float* betas = (const float*)d_in[7];
    float* out = (float*)d_out;

    int M  = in_sizes[0] / RANK;   // 50000
    int nE = in_sizes[1];          // 640000
    int nG = in_sizes[3];          // 50
    int M_pad = (M + 63) & ~63;

    char* ws = (char*)d_ws;
    size_t off = 0;
    auto alloc = [&](size_t bytes) {
        void* p = ws + off;
        off += (bytes + 255) & ~(size_t)255;
        return p;
    };
    int*   counts  = (int*)alloc((size_t)M * 4);
    int*   ends    = (int*)alloc((size_t)M * 4);
    int*   bsums   = (int*)alloc(256 * 4);
    float* invout  = (float*)alloc((size_t)M * 4);
    float* invin   = (float*)alloc((size_t)M * 4);
    int*   csr_src = (int*)alloc((size_t)nE * 4);
    short* Wt      = (short*)alloc((size_t)3 * 16384 * 2);
    short* B0      = (short*)alloc((size_t)M_pad * RANK * 2);
    short* B1      = (short*)alloc((size_t)M_pad * RANK * 2);
    int*   pdst    = (int*)alloc((size_t)ECH * BINS * 4);   // 13.1 MB
    int*   psrc    = (int*)alloc((size_t)ECH * BINS * 4);   // 13.1 MB

    int nb = (M + 255) / 256;

    // ---- atomic-free CSR build ----
    hist_part<<<dim3(ECH, NCH, 2), BT, 0, stream>>>(src, dst, pdst, psrc, nE);
    reduce_part<<<(M + 255) / 256, 256, 0, stream>>>(pdst, psrc, counts, invin, invout, M);
    scan1_kernel<<<nb, 256, 0, stream>>>(counts, ends, bsums, M);
    scan2_kernel<<<1, 256, 0, stream>>>(bsums, nb);
    scan3_kernel<<<nb, 256, 0, stream>>>(ends, bsums, M);
    offs_kernel<<<(M + 255) / 256, 256, 0, stream>>>(pdst, ends, counts, M);
    fill_sorted<<<dim3(ECH, NCH), BT, 0, stream>>>(src, dst, pdst, csr_src, nE);

    // ---- weight repack + feature conversion ----
    repack_kernel<<<24, 256, 0, stream>>>(Ws, Wt);
    convert_kernel<<<(M * 64 + 255) / 256, 256, 0, stream>>>(features, (unsigned*)B0, M * 64);

    // ---- 3 layers: B0 -> (gemm) -> B1 -> (gatherln) -> B0 ----
    for (int l = 0; l < 3; l++) {
        gemm_mfma<<<(M + 63) / 64, 256, 0, stream>>>(
            B0, Wt + (size_t)l * 16384, invout, (unsigned short*)B1, M);
        gatherln_kernel<<<(M + 3) / 4, 256, 0, stream>>>(
            (const unsigned*)B1, ends, csr_src, invin, bs + (size_t)l * RANK,
            gammas + (size_t)l * RANK, betas + (size_t)l * RANK, (unsigned*)B0, M);
    }

    gather_kernel<<<nG, RANK, 0, stream>>>((const unsigned short*)B0, bnn, out, nG);
}

// Round 7
// 258.592 us; speedup vs baseline: 1.0482x; 1.0482x over previous
//
#include <hip/hip_runtime.h>

#define RANK 128
#define LN_EPS 1e-5f

// CSR-build geometry (tuned for M=50000, nE=640000)
#define NCH 4
#define CHUNK 12800            // NCH*CHUNK = 51200 >= M ; LDS = 50 KB
#define BINS (NCH * CHUNK)
#define ECH 64                 // edge chunks
#define BT 1024                // threads per CSR-build block

using short8 = __attribute__((ext_vector_type(8))) short;
using v4f    = __attribute__((ext_vector_type(4))) float;

__device__ inline unsigned short f2bf(float f) {
    unsigned u = __float_as_uint(f);
    unsigned r = (u + 0x7FFF + ((u >> 16) & 1)) >> 16;   // RNE
    return (unsigned short)r;
}

// ---------------- partial histograms (no global atomics) ----------------
__global__ __launch_bounds__(BT) void hist_part(const int* __restrict__ src,
                                                const int* __restrict__ dst,
                                                int* __restrict__ pdst,
                                                int* __restrict__ psrc, int nE) {
    __shared__ int h[CHUNK];
    int c = blockIdx.x, n = blockIdx.y, z = blockIdx.z;
    const int* arr = z ? src : dst;
    int* pout = z ? psrc : pdst;
    int base = n * CHUNK;
    for (int i = threadIdx.x; i < CHUNK; i += BT) h[i] = 0;
    __syncthreads();
    int epc = (nE + ECH - 1) / ECH;
    int e0 = c * epc, e1 = min(e0 + epc, nE);
    for (int e = e0 + (int)threadIdx.x; e < e1; e += BT) {
        int v = arr[e] - base;
        if ((unsigned)v < (unsigned)CHUNK) atomicAdd(&h[v], 1);
    }
    __syncthreads();
    int* o = pout + (size_t)c * BINS + base;
    for (int i = threadIdx.x; i < CHUNK; i += BT) o[i] = h[i];
}

// ---------------- reduce partials -> counts + rsqrt normalizers ----------------
__global__ void reduce_part(const int* __restrict__ pdst, const int* __restrict__ psrc,
                            int* __restrict__ counts, float* __restrict__ invin,
                            float* __restrict__ invout, int M) {
    int b = blockIdx.x * blockDim.x + threadIdx.x;
    if (b >= M) return;
    int cd = 0, cs = 0;
#pragma unroll 8
    for (int c = 0; c < ECH; c++) {
        cd += pdst[(size_t)c * BINS + b];
        cs += psrc[(size_t)c * BINS + b];
    }
    counts[b] = cd;
    invin[b]  = rsqrtf(fmaxf((float)cd, 1.0f));
    invout[b] = rsqrtf(fmaxf((float)cs, 1.0f));
}

// ---------------- prefix scan (3-phase) -> inclusive ends ----------------
__global__ __launch_bounds__(256) void scan1_kernel(const int* __restrict__ counts,
                                                    int* __restrict__ ends,
                                                    int* __restrict__ bsums, int n) {
    __shared__ int tmp[256];
    int tid = threadIdx.x;
    int gid = blockIdx.x * 256 + tid;
    int v = (gid < n) ? counts[gid] : 0;
    tmp[tid] = v;
    __syncthreads();
    for (int off = 1; off < 256; off <<= 1) {
        int t = (tid >= off) ? tmp[tid - off] : 0;
        __syncthreads();
        tmp[tid] += t;
        __syncthreads();
    }
    if (gid < n) ends[gid] = tmp[tid];
    if (tid == 255) bsums[blockIdx.x] = tmp[255];
}

__global__ __launch_bounds__(256) void scan2_kernel(int* __restrict__ bsums, int nb) {
    __shared__ int tmp[256];
    int tid = threadIdx.x;
    int v = (tid < nb) ? bsums[tid] : 0;
    tmp[tid] = v;
    __syncthreads();
    for (int off = 1; off < 256; off <<= 1) {
        int t = (tid >= off) ? tmp[tid - off] : 0;
        __syncthreads();
        tmp[tid] += t;
        __syncthreads();
    }
    if (tid < nb) bsums[tid] = tmp[tid] - v;   // exclusive
}

__global__ __launch_bounds__(256) void scan3_kernel(int* __restrict__ ends,
                                                    const int* __restrict__ bsums, int n) {
    int gid = blockIdx.x * 256 + threadIdx.x;
    if (gid < n) ends[gid] += bsums[blockIdx.x];   // inclusive global ends
}

// ---------------- per-(chunk,bin) start offsets, in-place on pdst ----------------
__global__ void offs_kernel(int* __restrict__ pdst, const int* __restrict__ ends,
                            const int* __restrict__ counts, int M) {
    int b = blockIdx.x * blockDim.x + threadIdx.x;
    if (b >= M) return;
    int run = ends[b] - counts[b];
#pragma unroll 8
    for (int c = 0; c < ECH; c++) {
        size_t idx = (size_t)c * BINS + b;
        int t = pdst[idx];
        pdst[idx] = run;
        run += t;
    }
}

// ---------------- CSR fill via LDS cursors (no global atomics) ----------------
__global__ __launch_bounds__(BT) void fill_sorted(const int* __restrict__ src,
                                                  const int* __restrict__ dst,
                                                  const int* __restrict__ pdst,
                                                  int* __restrict__ csr_src, int nE) {
    __shared__ int cur[CHUNK];
    int c = blockIdx.x, n = blockIdx.y;
    int base = n * CHUNK;
    const int* o = pdst + (size_t)c * BINS + base;
    for (int i = threadIdx.x; i < CHUNK; i += BT) cur[i] = o[i];
    __syncthreads();
    int epc = (nE + ECH - 1) / ECH;
    int e0 = c * epc, e1 = min(e0 + epc, nE);
    for (int e = e0 + (int)threadIdx.x; e < e1; e += BT) {
        int d = dst[e] - base;
        if ((unsigned)d < (unsigned)CHUNK) {
            int pos = atomicAdd(&cur[d], 1);   // LDS atomic
            csr_src[pos] = src[e];
        }
    }
}

// ---------------- frontier: T3 = first_idx (ordered), bitmap, count ----------------
__global__ void mark3_kernel(const int* __restrict__ bnn, int nG,
                             int* __restrict__ T3, unsigned* __restrict__ bm3,
                             int* __restrict__ cnt3) {
    int lane = threadIdx.x & 63;
    if (nG <= 64) {
        int v = (lane < nG) ? bnn[lane] : 0;
        int orig = v;
#pragma unroll
        for (int off = 1; off < 64; off <<= 1) {
            int t = __shfl_up(v, off);
            if (lane >= off) v += t;
        }
        int excl = v - orig;
        if (lane < nG) {
            T3[lane] = excl;
            atomicOr(&bm3[excl >> 5], 1u << (excl & 31));
        }
        if (lane == 0) *cnt3 = nG;
    } else if (lane == 0) {
        int idx = 0;
        for (int g = 0; g < nG; g++) {
            T3[g] = idx;
            atomicOr(&bm3[idx >> 5], 1u << (idx & 31));
            idx += bnn[g];
        }
        *cnt3 = nG;
    }
}

// ---------------- frontier expansion: list of unique src with dst in bm_in ----------------
__global__ __launch_bounds__(256) void expand_kernel(const int* __restrict__ src,
                                                     const int* __restrict__ dst,
                                                     const unsigned* __restrict__ bm_in,
                                                     unsigned* __restrict__ bm_out,
                                                     int* __restrict__ list,
                                                     int* __restrict__ cnt, int nE) {
    int e = blockIdx.x * 256 + threadIdx.x;
    int u = 0;
    bool flag = false;
    if (e < nE) {
        int d = dst[e];
        if ((bm_in[d >> 5] >> (d & 31)) & 1) {
            u = src[e];
            unsigned old = atomicOr(&bm_out[u >> 5], 1u << (u & 31));
            flag = !((old >> (u & 31)) & 1);
        }
    }
    unsigned long long mask = __ballot(flag);
    if (mask) {
        int lane = threadIdx.x & 63;
        int leader = __ffsll((long long)mask) - 1;
        int base = 0;
        if (lane == leader) base = atomicAdd(cnt, __popcll(mask));
        base = __shfl(base, leader);
        if (flag) list[base + __popcll(mask & ((1ull << lane) - 1))] = u;
    }
}

// ---------------- features fp32 -> bf16, invout pre-scaled ----------------
__global__ void convert_scale(const float* __restrict__ X, const float* __restrict__ invout,
                              unsigned* __restrict__ Xs, int n2) {
    int i = blockIdx.x * blockDim.x + threadIdx.x;   // n2 = M*64 pairs
    if (i < n2) {
        float s = invout[i >> 6];
        float2 v = ((const float2*)X)[i];
        Xs[i] = (unsigned)f2bf(v.x * s) | ((unsigned)f2bf(v.y * s) << 16);
    }
}

// ---------------- W repack to MFMA B-fragment order ----------------
__global__ void repack_kernel(const float* __restrict__ Ws, short* __restrict__ Wt) {
    int l = blockIdx.x >> 3;
    int s = (blockIdx.x & 7) * 256 + threadIdx.x;
    int lane = s & 63, ct = (s >> 6) & 7, k0 = s >> 9;
    int m = lane & 15, quad = lane >> 4;
    const float* W = Ws + (size_t)l * RANK * RANK;
    short* o = Wt + (size_t)l * 16384 + (size_t)s * 8;
#pragma unroll
    for (int j = 0; j < 8; j++)
        o[j] = (short)f2bf(W[(k0 * 32 + quad * 8 + j) * RANK + ct * 16 + m]);
}

// ---------------- pruned CSR gather: AG[v] = sum of Fin rows (pre-scaled) ----------------
__global__ __launch_bounds__(256) void gather_agg(const unsigned* __restrict__ Fin,
                                                  const int* __restrict__ ends,
                                                  const int* __restrict__ csr_src,
                                                  const int* __restrict__ list,
                                                  const int* __restrict__ cnt,
                                                  unsigned* __restrict__ AG) {
    int lane = threadIdx.x & 63;
    int wg = blockIdx.x * 4 + (threadIdx.x >> 6);
    int nW = gridDim.x * 4;
    int seg = lane >> 4, m = lane & 15;
    int n = *cnt;

    for (int i = wg; i < n; i += nW) {
        int node = list[i];
        int end = ends[node];
        int e = (node == 0) ? 0 : ends[node - 1];

        float ax[8];
#pragma unroll
        for (int k = 0; k < 8; k++) ax[k] = 0.f;

        while (e < end) {
            int rem = end - e;
            int myi = 0;
            if (lane < rem) myi = csr_src[e + lane];
            int nn = min(rem, 64);
            int t = 0;
            for (; t + 16 <= nn; t += 16) {
                uint4 u[4];
#pragma unroll
                for (int gi = 0; gi < 4; gi++) {
                    int idx = __shfl(myi, t + gi * 4 + seg);
                    u[gi] = *(const uint4*)(Fin + (size_t)idx * 64 + m * 4);
                }
#pragma unroll
                for (int gi = 0; gi < 4; gi++) {
                    ax[0] += __uint_as_float(u[gi].x << 16);
                    ax[1] += __uint_as_float(u[gi].x & 0xFFFF0000u);
                    ax[2] += __uint_as_float(u[gi].y << 16);
                    ax[3] += __uint_as_float(u[gi].y & 0xFFFF0000u);
                    ax[4] += __uint_as_float(u[gi].z << 16);
                    ax[5] += __uint_as_float(u[gi].z & 0xFFFF0000u);
                    ax[6] += __uint_as_float(u[gi].w << 16);
                    ax[7] += __uint_as_float(u[gi].w & 0xFFFF0000u);
                }
            }
            for (; t < nn; t += 4) {
                bool act = (t + seg) < nn;
                int idx = __shfl(myi, (t + seg) & 63);
                if (act) {
                    uint4 u = *(const uint4*)(Fin + (size_t)idx * 64 + m * 4);
                    ax[0] += __uint_as_float(u.x << 16);
                    ax[1] += __uint_as_float(u.x & 0xFFFF0000u);
                    ax[2] += __uint_as_float(u.y << 16);
                    ax[3] += __uint_as_float(u.y & 0xFFFF0000u);
                    ax[4] += __uint_as_float(u.z << 16);
                    ax[5] += __uint_as_float(u.z & 0xFFFF0000u);
                    ax[6] += __uint_as_float(u.w << 16);
                    ax[7] += __uint_as_float(u.w & 0xFFFF0000u);
                }
            }
            e += nn;
        }

#pragma unroll
        for (int k = 0; k < 8; k++) {
            ax[k] += __shfl_xor(ax[k], 16);
            ax[k] += __shfl_xor(ax[k], 32);
        }
        if (seg == 0) {
            uint4 o;
            o.x = (unsigned)f2bf(ax[0]) | ((unsigned)f2bf(ax[1]) << 16);
            o.y = (unsigned)f2bf(ax[2]) | ((unsigned)f2bf(ax[3]) << 16);
            o.z = (unsigned)f2bf(ax[4]) | ((unsigned)f2bf(ax[5]) << 16);
            o.w = (unsigned)f2bf(ax[6]) | ((unsigned)f2bf(ax[7]) << 16);
            *(uint4*)(AG + (size_t)node * 64 + m * 4) = o;
        }
    }
}

// ---------------- fused GEMM (bf16 MFMA) + invin + bias + LN + ReLU ----------------
// wave per 16-row tile of the node list; LAST=1 writes fp32 to out in list order
template <int LAST>
__global__ __launch_bounds__(256) void gemm_ln(const short* __restrict__ AG,
                                               const short* __restrict__ Wt,
                                               const float* __restrict__ invin,
                                               const float* __restrict__ invout,
                                               const float* __restrict__ bias,
                                               const float* __restrict__ gamma,
                                               const float* __restrict__ beta,
                                               const int* __restrict__ list,
                                               const int* __restrict__ cnt,
                                               unsigned short* __restrict__ Fout,
                                               float* __restrict__ out) {
    int lane = threadIdx.x & 63;
    int m = lane & 15, quad = lane >> 4;
    int wg = blockIdx.x * 4 + (threadIdx.x >> 6);
    int nW = gridDim.x * 4;
    int n = *cnt;
    int tiles = (n + 15) >> 4;

    float bb[8], gg[8], pp[8];
#pragma unroll
    for (int ct = 0; ct < 8; ct++) {
        bb[ct] = bias[ct * 16 + m];
        gg[ct] = gamma[ct * 16 + m];
        pp[ct] = beta[ct * 16 + m];
    }

    for (int t = wg; t < tiles; t += nW) {
        int base = t * 16;
        int ra = min(base + m, n - 1);
        const short* arow = AG + (size_t)list[ra] * RANK + quad * 8;

        v4f acc[8];
#pragma unroll
        for (int ct = 0; ct < 8; ct++) acc[ct] = (v4f){0.f, 0.f, 0.f, 0.f};

#pragma unroll
        for (int k0 = 0; k0 < 4; k0++) {
            short8 a = *(const short8*)(arow + k0 * 32);
#pragma unroll
            for (int ct = 0; ct < 8; ct++) {
                short8 b = *(const short8*)(Wt + (size_t)((k0 * 8 + ct) * 64 + lane) * 8);
                acc[ct] = __builtin_amdgcn_mfma_f32_16x16x32_bf16(a, b, acc[ct], 0, 0, 0);
            }
        }

#pragma unroll
        for (int r = 0; r < 4; r++) {
            int gr = base + quad * 4 + r;
            bool valid = gr < n;
            int node = list[valid ? gr : (n - 1)];
            float iv = invin[node];
            float x[8];
            float sum = 0.f, sq = 0.f;
#pragma unroll
            for (int ct = 0; ct < 8; ct++) {
                float c = acc[ct][r] * iv + bb[ct];
                x[ct] = c;
                sum += c;
                sq += c * c;
            }
#pragma unroll
            for (int off = 1; off < 16; off <<= 1) {
                sum += __shfl_xor(sum, off);
                sq  += __shfl_xor(sq, off);
            }
            float mu = sum * (1.0f / RANK);
            float var = sq * (1.0f / RANK) - mu * mu;
            float rs = rsqrtf(var + LN_EPS);
            if (valid) {
                if (LAST) {
#pragma unroll
                    for (int ct = 0; ct < 8; ct++) {
                        float y = fmaxf((x[ct] - mu) * rs * gg[ct] + pp[ct], 0.f);
                        out[(size_t)gr * RANK + ct * 16 + m] = y;
                    }
                } else {
                    float so = invout[node];   // pre-scale for next layer's gather
#pragma unroll
                    for (int ct = 0; ct < 8; ct++) {
                        float y = fmaxf((x[ct] - mu) * rs * gg[ct] + pp[ct], 0.f);
                        Fout[(size_t)node * RANK + ct * 16 + m] = f2bf(y * so);
                    }
                }
            }
        }
    }
}

extern "C" void kernel_launch(void* const* d_in, const int* in_sizes, int n_in,
                              void* d_out, int out_size, void* d_ws, size_t ws_size,
                              hipStream_t stream) {
    const float* features = (const float*)d_in[0];
    const int* src = (const int*)d_in[1];
    const int* dst = (const int*)d_in[2];
    const int* bnn = (const int*)d_in[3];
    const float* Ws = (const float*)d_in[4];
    const float* bs = (const float*)d_in[5];
    const float* gammas = (const float*)d_in[6];
    const float* betas = (const float*)d_in[7];
    float* out = (float*)d_out;

    int M  = in_sizes[0] / RANK;   // 50000
    int nE = in_sizes[1];          // 640000
    int nG = in_sizes[3];          // 50
    int bmw = (M + 31) / 32;       // bitmap words

    char* ws = (char*)d_ws;
    size_t off = 0;
    auto alloc = [&](size_t bytes) {
        void* p = ws + off;
        off += (bytes + 255) & ~(size_t)255;
        return p;
    };
    int*   counts  = (int*)alloc((size_t)M * 4);
    int*   ends    = (int*)alloc((size_t)M * 4);
    int*   bsums   = (int*)alloc(256 * 4);
    float* invout  = (float*)alloc((size_t)M * 4);
    float* invin   = (float*)alloc((size_t)M * 4);
    int*   csr_src = (int*)alloc((size_t)nE * 4);
    short* Wt      = (short*)alloc((size_t)3 * 16384 * 2);
    short* Xs      = (short*)alloc((size_t)M * RANK * 2);
    short* AG      = (short*)alloc((size_t)M * RANK * 2);
    short* F       = (short*)alloc((size_t)M * RANK * 2);
    int*   pdst    = (int*)alloc((size_t)ECH * BINS * 4);
    int*   psrc    = (int*)alloc((size_t)ECH * BINS * 4);
    // zero-region: bitmaps + counters (one memset)
    char*  zbase   = (char*)alloc((size_t)(3 * bmw + 8) * 4);
    unsigned* bm3  = (unsigned*)zbase;
    unsigned* bm2  = bm3 + bmw;
    unsigned* bm1  = bm2 + bmw;
    int*   cnt2    = (int*)(bm1 + bmw);
    int*   cnt1    = cnt2 + 1;
    int*   cnt3    = (int*)alloc(256);          // written unconditionally
    int*   T3      = (int*)alloc((size_t)((nG + 63) & ~63) * 4);
    int*   T2      = (int*)alloc((size_t)M * 4);
    int*   T1      = (int*)alloc((size_t)M * 4);

    int nb = (M + 255) / 256;
    int eb = (nE + 255) / 256;

    hipMemsetAsync(zbase, 0, (size_t)(3 * bmw + 8) * 4, stream);

    // ---- full CSR build (also yields degree normalizers) ----
    hist_part<<<dim3(ECH, NCH, 2), BT, 0, stream>>>(src, dst, pdst, psrc, nE);
    reduce_part<<<nb, 256, 0, stream>>>(pdst, psrc, counts, invin, invout, M);
    scan1_kernel<<<nb, 256, 0, stream>>>(counts, ends, bsums, M);
    scan2_kernel<<<1, 256, 0, stream>>>(bsums, nb);
    scan3_kernel<<<nb, 256, 0, stream>>>(ends, bsums, M);
    offs_kernel<<<nb, 256, 0, stream>>>(pdst, ends, counts, M);
    fill_sorted<<<dim3(ECH, NCH), BT, 0, stream>>>(src, dst, pdst, csr_src, nE);

    // ---- frontier sets (backward reachability from first_idx) ----
    mark3_kernel<<<1, 64, 0, stream>>>(bnn, nG, T3, bm3, cnt3);
    expand_kernel<<<eb, 256, 0, stream>>>(src, dst, bm3, bm2, T2, cnt2, nE);
    expand_kernel<<<eb, 256, 0, stream>>>(src, dst, bm2, bm1, T1, cnt1, nE);

    // ---- weights + pre-scaled bf16 features ----
    repack_kernel<<<24, 256, 0, stream>>>(Ws, Wt);
    convert_scale<<<(M * 64 + 255) / 256, 256, 0, stream>>>(features, invout, (unsigned*)Xs, M * 64);

    // ---- pruned layers ----
    gather_agg<<<256, 256, 0, stream>>>((const unsigned*)Xs, ends, csr_src, T1, cnt1, (unsigned*)AG);
    gemm_ln<0><<<128, 256, 0, stream>>>(AG, Wt, invin, invout,
                                        bs, gammas, betas, T1, cnt1, (unsigned short*)F, nullptr);
    gather_agg<<<64, 256, 0, stream>>>((const unsigned*)F, ends, csr_src, T2, cnt2, (unsigned*)AG);
    gemm_ln<0><<<16, 256, 0, stream>>>(AG, Wt + 16384, invin, invout,
                                       bs + RANK, gammas + RANK, betas + RANK, T2, cnt2,
                                       (unsigned short*)F, nullptr);
    gather_agg<<<16, 256, 0, stream>>>((const unsigned*)F, ends, csr_src, T3, cnt3, (unsigned*)AG);
    gemm_ln<1><<<1, 256, 0, stream>>>(AG, Wt + 32768, invin, invout,
                                      bs + 2 * RANK, gammas + 2 * RANK, betas + 2 * RANK, T3, cnt3,
                                      nullptr, out);
}

// Round 8
// 201.708 us; speedup vs baseline: 1.3438x; 1.2820x over previous
//
#include <hip/hip_runtime.h>

#define RANK 128
#define LN_EPS 1e-5f

// CSR-build geometry (tuned for M=50000, nE=640000)
#define NCH 4
#define CHUNK 12800            // NCH*CHUNK = 51200 >= M ; LDS = 50 KB
#define BINS (NCH * CHUNK)
#define ECH 64                 // edge chunks
#define BT 1024                // threads per CSR-build block

using short8 = __attribute__((ext_vector_type(8))) short;
using v4f    = __attribute__((ext_vector_type(4))) float;

__device__ inline unsigned short f2bf(float f) {
    unsigned u = __float_as_uint(f);
    unsigned r = (u + 0x7FFF + ((u >> 16) & 1)) >> 16;   // RNE
    return (unsigned short)r;
}

// ---------------- partial histograms (no global atomics) ----------------
__global__ __launch_bounds__(BT) void hist_part(const int* __restrict__ src,
                                                const int* __restrict__ dst,
                                                int* __restrict__ pdst,
                                                int* __restrict__ psrc, int nE) {
    __shared__ int h[CHUNK];
    int c = blockIdx.x, n = blockIdx.y, z = blockIdx.z;
    const int* arr = z ? src : dst;
    int* pout = z ? psrc : pdst;
    int base = n * CHUNK;
    for (int i = threadIdx.x; i < CHUNK; i += BT) h[i] = 0;
    __syncthreads();
    int epc = (nE + ECH - 1) / ECH;
    int e0 = c * epc, e1 = min(e0 + epc, nE);
    for (int e = e0 + (int)threadIdx.x; e < e1; e += BT) {
        int v = arr[e] - base;
        if ((unsigned)v < (unsigned)CHUNK) atomicAdd(&h[v], 1);
    }
    __syncthreads();
    int* o = pout + (size_t)c * BINS + base;
    for (int i = threadIdx.x; i < CHUNK; i += BT) o[i] = h[i];
}

// ---------------- reduce partials -> counts + rsqrt normalizers ----------------
__global__ void reduce_part(const int* __restrict__ pdst, const int* __restrict__ psrc,
                            int* __restrict__ counts, float* __restrict__ invin,
                            float* __restrict__ invout, int M) {
    int b = blockIdx.x * blockDim.x + threadIdx.x;
    if (b >= M) return;
    int cd = 0, cs = 0;
#pragma unroll 8
    for (int c = 0; c < ECH; c++) {
        cd += pdst[(size_t)c * BINS + b];
        cs += psrc[(size_t)c * BINS + b];
    }
    counts[b] = cd;
    invin[b]  = rsqrtf(fmaxf((float)cd, 1.0f));
    invout[b] = rsqrtf(fmaxf((float)cs, 1.0f));
}

// ---------------- prefix scan (3-phase) -> inclusive ends ----------------
__global__ __launch_bounds__(256) void scan1_kernel(const int* __restrict__ counts,
                                                    int* __restrict__ ends,
                                                    int* __restrict__ bsums, int n) {
    __shared__ int tmp[256];
    int tid = threadIdx.x;
    int gid = blockIdx.x * 256 + tid;
    int v = (gid < n) ? counts[gid] : 0;
    tmp[tid] = v;
    __syncthreads();
    for (int off = 1; off < 256; off <<= 1) {
        int t = (tid >= off) ? tmp[tid - off] : 0;
        __syncthreads();
        tmp[tid] += t;
        __syncthreads();
    }
    if (gid < n) ends[gid] = tmp[tid];
    if (tid == 255) bsums[blockIdx.x] = tmp[255];
}

__global__ __launch_bounds__(256) void scan2_kernel(int* __restrict__ bsums, int nb) {
    __shared__ int tmp[256];
    int tid = threadIdx.x;
    int v = (tid < nb) ? bsums[tid] : 0;
    tmp[tid] = v;
    __syncthreads();
    for (int off = 1; off < 256; off <<= 1) {
        int t = (tid >= off) ? tmp[tid - off] : 0;
        __syncthreads();
        tmp[tid] += t;
        __syncthreads();
    }
    if (tid < nb) bsums[tid] = tmp[tid] - v;   // exclusive
}

__global__ __launch_bounds__(256) void scan3_kernel(int* __restrict__ ends,
                                                    const int* __restrict__ bsums, int n) {
    int gid = blockIdx.x * 256 + threadIdx.x;
    if (gid < n) ends[gid] += bsums[blockIdx.x];   // inclusive global ends
}

// ---------------- per-(chunk,bin) start offsets, in-place on pdst ----------------
__global__ void offs_kernel(int* __restrict__ pdst, const int* __restrict__ ends,
                            const int* __restrict__ counts, int M) {
    int b = blockIdx.x * blockDim.x + threadIdx.x;
    if (b >= M) return;
    int run = ends[b] - counts[b];
#pragma unroll 8
    for (int c = 0; c < ECH; c++) {
        size_t idx = (size_t)c * BINS + b;
        int t = pdst[idx];
        pdst[idx] = run;
        run += t;
    }
}

// ---------------- CSR fill via LDS cursors (no global atomics) ----------------
__global__ __launch_bounds__(BT) void fill_sorted(const int* __restrict__ src,
                                                  const int* __restrict__ dst,
                                                  const int* __restrict__ pdst,
                                                  int* __restrict__ csr_src, int nE) {
    __shared__ int cur[CHUNK];
    int c = blockIdx.x, n = blockIdx.y;
    int base = n * CHUNK;
    const int* o = pdst + (size_t)c * BINS + base;
    for (int i = threadIdx.x; i < CHUNK; i += BT) cur[i] = o[i];
    __syncthreads();
    int epc = (nE + ECH - 1) / ECH;
    int e0 = c * epc, e1 = min(e0 + epc, nE);
    for (int e = e0 + (int)threadIdx.x; e < e1; e += BT) {
        int d = dst[e] - base;
        if ((unsigned)d < (unsigned)CHUNK) {
            int pos = atomicAdd(&cur[d], 1);   // LDS atomic
            csr_src[pos] = src[e];
        }
    }
}

// ---------------- frontier: T3 = first_idx (ordered), bitmap, count ----------------
__global__ void mark3_kernel(const int* __restrict__ bnn, int nG,
                             int* __restrict__ T3, unsigned* __restrict__ bm3,
                             int* __restrict__ cnt3) {
    int lane = threadIdx.x & 63;
    if (nG <= 64) {
        int v = (lane < nG) ? bnn[lane] : 0;
        int orig = v;
#pragma unroll
        for (int off = 1; off < 64; off <<= 1) {
            int t = __shfl_up(v, off);
            if (lane >= off) v += t;
        }
        int excl = v - orig;
        if (lane < nG) {
            T3[lane] = excl;
            atomicOr(&bm3[excl >> 5], 1u << (excl & 31));
        }
        if (lane == 0) *cnt3 = nG;
    } else if (lane == 0) {
        int idx = 0;
        for (int g = 0; g < nG; g++) {
            T3[g] = idx;
            atomicOr(&bm3[idx >> 5], 1u << (idx & 31));
            idx += bnn[g];
        }
        *cnt3 = nG;
    }
}

// ---------------- frontier via CSR: out = unique sources of in-edges of list ----------------
// wave per list node; lanes walk csr range; wave-aggregated append
__global__ __launch_bounds__(256) void frontier_csr(const int* __restrict__ list,
                                                    const int* __restrict__ cnt,
                                                    const int* __restrict__ ends,
                                                    const int* __restrict__ csr_src,
                                                    unsigned* __restrict__ bm_out,
                                                    int* __restrict__ out_list,
                                                    int* __restrict__ out_cnt) {
    int lane = threadIdx.x & 63;
    int wg = blockIdx.x * 4 + (threadIdx.x >> 6);
    int nW = gridDim.x * 4;
    int n = *cnt;
    for (int i = wg; i < n; i += nW) {
        int node = list[i];
        int end = ends[node];
        int beg = (node == 0) ? 0 : ends[node - 1];
        for (int e0 = beg; e0 < end; e0 += 64) {
            int u = 0;
            bool flag = false;
            if (e0 + lane < end) {
                u = csr_src[e0 + lane];
                unsigned old = atomicOr(&bm_out[u >> 5], 1u << (u & 31));
                flag = !((old >> (u & 31)) & 1);
            }
            unsigned long long mask = __ballot(flag);
            if (mask) {
                int leader = __ffsll((long long)mask) - 1;
                int base = 0;
                if (lane == leader) base = atomicAdd(out_cnt, __popcll(mask));
                base = __shfl(base, leader);
                if (flag) out_list[base + __popcll(mask & ((1ull << lane) - 1))] = u;
            }
        }
    }
}

// ---------------- features fp32 -> bf16, invout pre-scaled ----------------
__global__ void convert_scale(const float* __restrict__ X, const float* __restrict__ invout,
                              unsigned* __restrict__ Xs, int n2) {
    int i = blockIdx.x * blockDim.x + threadIdx.x;   // n2 = M*64 pairs
    if (i < n2) {
        float s = invout[i >> 6];
        float2 v = ((const float2*)X)[i];
        Xs[i] = (unsigned)f2bf(v.x * s) | ((unsigned)f2bf(v.y * s) << 16);
    }
}

// ---------------- W repack to MFMA B-fragment order ----------------
__global__ void repack_kernel(const float* __restrict__ Ws, short* __restrict__ Wt) {
    int l = blockIdx.x >> 3;
    int s = (blockIdx.x & 7) * 256 + threadIdx.x;
    int lane = s & 63, ct = (s >> 6) & 7, k0 = s >> 9;
    int m = lane & 15, quad = lane >> 4;
    const float* W = Ws + (size_t)l * RANK * RANK;
    short* o = Wt + (size_t)l * 16384 + (size_t)s * 8;
#pragma unroll
    for (int j = 0; j < 8; j++)
        o[j] = (short)f2bf(W[(k0 * 32 + quad * 8 + j) * RANK + ct * 16 + m]);
}

// ---------------- pruned CSR gather: AG[v] = sum of Fin rows (pre-scaled) ----------------
__global__ __launch_bounds__(256) void gather_agg(const unsigned* __restrict__ Fin,
                                                  const int* __restrict__ ends,
                                                  const int* __restrict__ csr_src,
                                                  const int* __restrict__ list,
                                                  const int* __restrict__ cnt,
                                                  unsigned* __restrict__ AG) {
    int lane = threadIdx.x & 63;
    int wg = blockIdx.x * 4 + (threadIdx.x >> 6);
    int nW = gridDim.x * 4;
    int seg = lane >> 4, m = lane & 15;
    int n = *cnt;

    for (int i = wg; i < n; i += nW) {
        int node = list[i];
        int end = ends[node];
        int e = (node == 0) ? 0 : ends[node - 1];

        float ax[8];
#pragma unroll
        for (int k = 0; k < 8; k++) ax[k] = 0.f;

        while (e < end) {
            int rem = end - e;
            int myi = 0;
            if (lane < rem) myi = csr_src[e + lane];
            int nn = min(rem, 64);
            int t = 0;
            for (; t + 16 <= nn; t += 16) {
                uint4 u[4];
#pragma unroll
                for (int gi = 0; gi < 4; gi++) {
                    int idx = __shfl(myi, t + gi * 4 + seg);
                    u[gi] = *(const uint4*)(Fin + (size_t)idx * 64 + m * 4);
                }
#pragma unroll
                for (int gi = 0; gi < 4; gi++) {
                    ax[0] += __uint_as_float(u[gi].x << 16);
                    ax[1] += __uint_as_float(u[gi].x & 0xFFFF0000u);
                    ax[2] += __uint_as_float(u[gi].y << 16);
                    ax[3] += __uint_as_float(u[gi].y & 0xFFFF0000u);
                    ax[4] += __uint_as_float(u[gi].z << 16);
                    ax[5] += __uint_as_float(u[gi].z & 0xFFFF0000u);
                    ax[6] += __uint_as_float(u[gi].w << 16);
                    ax[7] += __uint_as_float(u[gi].w & 0xFFFF0000u);
                }
            }
            for (; t < nn; t += 4) {
                bool act = (t + seg) < nn;
                int idx = __shfl(myi, (t + seg) & 63);
                if (act) {
                    uint4 u = *(const uint4*)(Fin + (size_t)idx * 64 + m * 4);
                    ax[0] += __uint_as_float(u.x << 16);
                    ax[1] += __uint_as_float(u.x & 0xFFFF0000u);
                    ax[2] += __uint_as_float(u.y << 16);
                    ax[3] += __uint_as_float(u.y & 0xFFFF0000u);
                    ax[4] += __uint_as_float(u.z << 16);
                    ax[5] += __uint_as_float(u.z & 0xFFFF0000u);
                    ax[6] += __uint_as_float(u.w << 16);
                    ax[7] += __uint_as_float(u.w & 0xFFFF0000u);
                }
            }
            e += nn;
        }

#pragma unroll
        for (int k = 0; k < 8; k++) {
            ax[k] += __shfl_xor(ax[k], 16);
            ax[k] += __shfl_xor(ax[k], 32);
        }
        if (seg == 0) {
            uint4 o;
            o.x = (unsigned)f2bf(ax[0]) | ((unsigned)f2bf(ax[1]) << 16);
            o.y = (unsigned)f2bf(ax[2]) | ((unsigned)f2bf(ax[3]) << 16);
            o.z = (unsigned)f2bf(ax[4]) | ((unsigned)f2bf(ax[5]) << 16);
            o.w = (unsigned)f2bf(ax[6]) | ((unsigned)f2bf(ax[7]) << 16);
            *(uint4*)(AG + (size_t)node * 64 + m * 4) = o;
        }
    }
}

// ---------------- fused GEMM (bf16 MFMA) + invin + bias + LN + ReLU ----------------
// wave per 16-row tile of the node list; LAST=1 writes fp32 to out in list order
template <int LAST>
__global__ __launch_bounds__(256) void gemm_ln(const short* __restrict__ AG,
                                               const short* __restrict__ Wt,
                                               const float* __restrict__ invin,
                                               const float* __restrict__ invout,
                                               const float* __restrict__ bias,
                                               const float* __restrict__ gamma,
                                               const float* __restrict__ beta,
                                               const int* __restrict__ list,
                                               const int* __restrict__ cnt,
                                               unsigned short* __restrict__ Fout,
                                               float* __restrict__ out) {
    int lane = threadIdx.x & 63;
    int m = lane & 15, quad = lane >> 4;
    int wg = blockIdx.x * 4 + (threadIdx.x >> 6);
    int nW = gridDim.x * 4;
    int n = *cnt;
    int tiles = (n + 15) >> 4;

    float bb[8], gg[8], pp[8];
#pragma unroll
    for (int ct = 0; ct < 8; ct++) {
        bb[ct] = bias[ct * 16 + m];
        gg[ct] = gamma[ct * 16 + m];
        pp[ct] = beta[ct * 16 + m];
    }

    for (int t = wg; t < tiles; t += nW) {
        int base = t * 16;
        int ra = min(base + m, n - 1);
        const short* arow = AG + (size_t)list[ra] * RANK + quad * 8;

        v4f acc[8];
#pragma unroll
        for (int ct = 0; ct < 8; ct++) acc[ct] = (v4f){0.f, 0.f, 0.f, 0.f};

#pragma unroll
        for (int k0 = 0; k0 < 4; k0++) {
            short8 a = *(const short8*)(arow + k0 * 32);
#pragma unroll
            for (int ct = 0; ct < 8; ct++) {
                short8 b = *(const short8*)(Wt + (size_t)((k0 * 8 + ct) * 64 + lane) * 8);
                acc[ct] = __builtin_amdgcn_mfma_f32_16x16x32_bf16(a, b, acc[ct], 0, 0, 0);
            }
        }

#pragma unroll
        for (int r = 0; r < 4; r++) {
            int gr = base + quad * 4 + r;
            bool valid = gr < n;
            int node = list[valid ? gr : (n - 1)];
            float iv = invin[node];
            float x[8];
            float sum = 0.f, sq = 0.f;
#pragma unroll
            for (int ct = 0; ct < 8; ct++) {
                float c = acc[ct][r] * iv + bb[ct];
                x[ct] = c;
                sum += c;
                sq += c * c;
            }
#pragma unroll
            for (int off = 1; off < 16; off <<= 1) {
                sum += __shfl_xor(sum, off);
                sq  += __shfl_xor(sq, off);
            }
            float mu = sum * (1.0f / RANK);
            float var = sq * (1.0f / RANK) - mu * mu;
            float rs = rsqrtf(var + LN_EPS);
            if (valid) {
                if (LAST) {
#pragma unroll
                    for (int ct = 0; ct < 8; ct++) {
                        float y = fmaxf((x[ct] - mu) * rs * gg[ct] + pp[ct], 0.f);
                        out[(size_t)gr * RANK + ct * 16 + m] = y;
                    }
                } else {
                    float so = invout[node];   // pre-scale for next layer's gather
#pragma unroll
                    for (int ct = 0; ct < 8; ct++) {
                        float y = fmaxf((x[ct] - mu) * rs * gg[ct] + pp[ct], 0.f);
                        Fout[(size_t)node * RANK + ct * 16 + m] = f2bf(y * so);
                    }
                }
            }
        }
    }
}

extern "C" void kernel_launch(void* const* d_in, const int* in_sizes, int n_in,
                              void* d_out, int out_size, void* d_ws, size_t ws_size,
                              hipStream_t stream) {
    const float* features = (const float*)d_in[0];
    const int* src = (const int*)d_in[1];
    const int* dst = (const int*)d_in[2];
    const int* bnn = (const int*)d_in[3];
    const float* Ws = (const float*)d_in[4];
    const float* bs = (const float*)d_in[5];
    const float* gammas = (const float*)d_in[6];
    const float* betas = (const float*)d_in[7];
    float* out = (float*)d_out;

    int M  = in_sizes[0] / RANK;   // 50000
    int nE = in_sizes[1];          // 640000
    int nG = in_sizes[3];          // 50
    int bmw = (M + 31) / 32;       // bitmap words

    char* ws = (char*)d_ws;
    size_t off = 0;
    auto alloc = [&](size_t bytes) {
        void* p = ws + off;
        off += (bytes + 255) & ~(size_t)255;
        return p;
    };
    int*   counts  = (int*)alloc((size_t)M * 4);
    int*   ends    = (int*)alloc((size_t)M * 4);
    int*   bsums   = (int*)alloc(256 * 4);
    float* invout  = (float*)alloc((size_t)M * 4);
    float* invin   = (float*)alloc((size_t)M * 4);
    int*   csr_src = (int*)alloc((size_t)nE * 4);
    short* Wt      = (short*)alloc((size_t)3 * 16384 * 2);
    short* Xs      = (short*)alloc((size_t)M * RANK * 2);
    short* AG      = (short*)alloc((size_t)M * RANK * 2);
    short* F       = (short*)alloc((size_t)M * RANK * 2);
    int*   pdst    = (int*)alloc((size_t)ECH * BINS * 4);
    int*   psrc    = (int*)alloc((size_t)ECH * BINS * 4);
    // zero-region: bitmaps + counters (one memset)
    char*  zbase   = (char*)alloc((size_t)(3 * bmw + 8) * 4);
    unsigned* bm3  = (unsigned*)zbase;
    unsigned* bm2  = bm3 + bmw;
    unsigned* bm1  = bm2 + bmw;
    int*   cnt2    = (int*)(bm1 + bmw);
    int*   cnt1    = cnt2 + 1;
    int*   cnt3    = (int*)alloc(256);          // written unconditionally
    int*   T3      = (int*)alloc((size_t)((nG + 63) & ~63) * 4);
    int*   T2      = (int*)alloc((size_t)M * 4);
    int*   T1      = (int*)alloc((size_t)M * 4);

    int nb = (M + 255) / 256;

    hipMemsetAsync(zbase, 0, (size_t)(3 * bmw + 8) * 4, stream);

    // ---- full CSR build (also yields degree normalizers) ----
    hist_part<<<dim3(ECH, NCH, 2), BT, 0, stream>>>(src, dst, pdst, psrc, nE);
    reduce_part<<<nb, 256, 0, stream>>>(pdst, psrc, counts, invin, invout, M);
    scan1_kernel<<<nb, 256, 0, stream>>>(counts, ends, bsums, M);
    scan2_kernel<<<1, 256, 0, stream>>>(bsums, nb);
    scan3_kernel<<<nb, 256, 0, stream>>>(ends, bsums, M);
    offs_kernel<<<nb, 256, 0, stream>>>(pdst, ends, counts, M);
    fill_sorted<<<dim3(ECH, NCH), BT, 0, stream>>>(src, dst, pdst, csr_src, nE);

    // ---- frontier sets via CSR ranges (backward reachability from first_idx) ----
    mark3_kernel<<<1, 64, 0, stream>>>(bnn, nG, T3, bm3, cnt3);
    frontier_csr<<<16, 256, 0, stream>>>(T3, cnt3, ends, csr_src, bm2, T2, cnt2);
    frontier_csr<<<64, 256, 0, stream>>>(T2, cnt2, ends, csr_src, bm1, T1, cnt1);

    // ---- weights + pre-scaled bf16 features ----
    repack_kernel<<<24, 256, 0, stream>>>(Ws, Wt);
    convert_scale<<<(M * 64 + 255) / 256, 256, 0, stream>>>(features, invout, (unsigned*)Xs, M * 64);

    // ---- pruned layers ----
    gather_agg<<<256, 256, 0, stream>>>((const unsigned*)Xs, ends, csr_src, T1, cnt1, (unsigned*)AG);
    gemm_ln<0><<<128, 256, 0, stream>>>(AG, Wt, invin, invout,
                                        bs, gammas, betas, T1, cnt1, (unsigned short*)F, nullptr);
    gather_agg<<<64, 256, 0, stream>>>((const unsigned*)F, ends, csr_src, T2, cnt2, (unsigned*)AG);
    gemm_ln<0><<<16, 256, 0, stream>>>(AG, Wt + 16384, invin, invout,
                                       bs + RANK, gammas + RANK, betas + RANK, T2, cnt2,
                                       (unsigned short*)F, nullptr);
    gather_agg<<<16, 256, 0, stream>>>((const unsigned*)F, ends, csr_src, T3, cnt3, (unsigned*)AG);
    gemm_ln<1><<<1, 256, 0, stream>>>(AG, Wt + 32768, invin, invout,
                                      bs + 2 * RANK, gammas + 2 * RANK, betas + 2 * RANK, T3, cnt3,
                                      nullptr, out);
}

// Round 9
// 191.410 us; speedup vs baseline: 1.4161x; 1.0538x over previous
//
#include <hip/hip_runtime.h>

#define RANK 128
#define LN_EPS 1e-5f

// CSR-build geometry (tuned for M=50000, nE=640000)
#define NCH 4
#define CHUNK 12800            // NCH*CHUNK = 51200 >= M ; LDS = 50 KB
#define BINS (NCH * CHUNK)
#define ECH 64                 // edge chunks
#define BT 1024                // threads per CSR-build block
#define BMWL ((BINS + 31) / 32) // LDS bitmap words (6.4 KB)

using short8 = __attribute__((ext_vector_type(8))) short;
using v4f    = __attribute__((ext_vector_type(4))) float;

__device__ inline unsigned short f2bf(float f) {
    unsigned u = __float_as_uint(f);
    unsigned r = (u + 0x7FFF + ((u >> 16) & 1)) >> 16;   // RNE
    return (unsigned short)r;
}

// ---------------- partial histograms (no global atomics) ----------------
__global__ __launch_bounds__(BT) void hist_part(const int* __restrict__ src,
                                                const int* __restrict__ dst,
                                                int* __restrict__ pdst,
                                                int* __restrict__ psrc, int nE) {
    __shared__ int h[CHUNK];
    int c = blockIdx.x, n = blockIdx.y, z = blockIdx.z;
    const int* arr = z ? src : dst;
    int* pout = z ? psrc : pdst;
    int base = n * CHUNK;
    for (int i = threadIdx.x; i < CHUNK; i += BT) h[i] = 0;
    __syncthreads();
    int epc = (nE + ECH - 1) / ECH;
    int e0 = c * epc, e1 = min(e0 + epc, nE);
    for (int e = e0 + (int)threadIdx.x; e < e1; e += BT) {
        int v = arr[e] - base;
        if ((unsigned)v < (unsigned)CHUNK) atomicAdd(&h[v], 1);
    }
    __syncthreads();
    int* o = pout + (size_t)c * BINS + base;
    for (int i = threadIdx.x; i < CHUNK; i += BT) o[i] = h[i];
}

// ------- reduce partials -> counts/invin/invout + in-block inclusive scan -------
__global__ __launch_bounds__(256) void reduce_scan1(const int* __restrict__ pdst,
                                                    const int* __restrict__ psrc,
                                                    int* __restrict__ counts,
                                                    float* __restrict__ invin,
                                                    float* __restrict__ invout,
                                                    int* __restrict__ ends,
                                                    int* __restrict__ bsums, int M) {
    __shared__ int tmp[256];
    int tid = threadIdx.x;
    int gid = blockIdx.x * 256 + tid;
    int cd = 0, cs = 0;
    if (gid < M) {
#pragma unroll 8
        for (int c = 0; c < ECH; c++) {
            cd += pdst[(size_t)c * BINS + gid];
            cs += psrc[(size_t)c * BINS + gid];
        }
        counts[gid] = cd;
        invin[gid]  = rsqrtf(fmaxf((float)cd, 1.0f));
        invout[gid] = rsqrtf(fmaxf((float)cs, 1.0f));
    }
    tmp[tid] = cd;
    __syncthreads();
    for (int off = 1; off < 256; off <<= 1) {
        int t = (tid >= off) ? tmp[tid - off] : 0;
        __syncthreads();
        tmp[tid] += t;
        __syncthreads();
    }
    if (gid < M) ends[gid] = tmp[tid];
    if (tid == 255) bsums[blockIdx.x] = tmp[255];
}

// ------- global scan finish + per-(chunk,bin) cursor rewrite (in-place pdst) -------
__global__ __launch_bounds__(256) void scan23_offs(int* __restrict__ ends,
                                                   const int* __restrict__ counts,
                                                   const int* __restrict__ bsums,
                                                   int* __restrict__ pdst, int nb, int M) {
    __shared__ int red[256];
    int tid = threadIdx.x;
    int b = blockIdx.x;
    red[tid] = (tid < b && tid < nb) ? bsums[tid] : 0;   // nb <= 256
    __syncthreads();
    for (int off = 128; off > 0; off >>= 1) {
        if (tid < off) red[tid] += red[tid + off];
        __syncthreads();
    }
    int prefix = red[0];
    int gid = b * 256 + tid;
    if (gid < M) {
        int e = ends[gid] + prefix;   // inclusive global end
        ends[gid] = e;
        int run = e - counts[gid];    // exclusive start
#pragma unroll 8
        for (int c = 0; c < ECH; c++) {
            size_t idx = (size_t)c * BINS + gid;
            int t = pdst[idx];
            pdst[idx] = run;
            run += t;
        }
    }
}

// ---------------- CSR fill via LDS cursors (no global atomics) ----------------
__global__ __launch_bounds__(BT) void fill_sorted(const int* __restrict__ src,
                                                  const int* __restrict__ dst,
                                                  const int* __restrict__ pdst,
                                                  int* __restrict__ csr_src, int nE) {
    __shared__ int cur[CHUNK];
    int c = blockIdx.x, n = blockIdx.y;
    int base = n * CHUNK;
    const int* o = pdst + (size_t)c * BINS + base;
    for (int i = threadIdx.x; i < CHUNK; i += BT) cur[i] = o[i];
    __syncthreads();
    int epc = (nE + ECH - 1) / ECH;
    int e0 = c * epc, e1 = min(e0 + epc, nE);
    for (int e = e0 + (int)threadIdx.x; e < e1; e += BT) {
        int d = dst[e] - base;
        if ((unsigned)d < (unsigned)CHUNK) {
            int pos = atomicAdd(&cur[d], 1);   // LDS atomic
            csr_src[pos] = src[e];
        }
    }
}

// ------- T3 build + T3->T2 frontier in one single-block kernel (LDS bitmap) -------
__global__ __launch_bounds__(256) void mark_expand3(const int* __restrict__ bnn, int nG,
                                                    const int* __restrict__ ends,
                                                    const int* __restrict__ csr_src,
                                                    int* __restrict__ T3, int* __restrict__ cnt3,
                                                    int* __restrict__ T2, int* __restrict__ cnt2) {
    __shared__ unsigned bm[BMWL];
    __shared__ int lcnt;
    int tid = threadIdx.x;
    for (int i = tid; i < BMWL; i += 256) bm[i] = 0;
    if (tid == 0) lcnt = 0;
    __syncthreads();
    if (tid < 64) {
        int lane = tid;
        if (nG <= 64) {
            int v = (lane < nG) ? bnn[lane] : 0;
            int orig = v;
#pragma unroll
            for (int off = 1; off < 64; off <<= 1) {
                int t = __shfl_up(v, off);
                if (lane >= off) v += t;
            }
            int excl = v - orig;
            if (lane < nG) T3[lane] = excl;
            if (lane == 0) *cnt3 = nG;
        } else if (lane == 0) {
            int idx = 0;
            for (int g = 0; g < nG; g++) { T3[g] = idx; idx += bnn[g]; }
            *cnt3 = nG;
        }
    }
    __syncthreads();
    int lane = tid & 63, w = tid >> 6;
    for (int i = w; i < nG; i += 4) {
        int node = T3[i];
        int end = ends[node];
        int beg = (node == 0) ? 0 : ends[node - 1];
        for (int e0 = beg; e0 < end; e0 += 64) {
            if (e0 + lane < end) {
                int u = csr_src[e0 + lane];
                unsigned old = atomicOr(&bm[u >> 5], 1u << (u & 31));   // LDS
                if (!((old >> (u & 31)) & 1)) {
                    int pos = atomicAdd(&lcnt, 1);                      // LDS
                    T2[pos] = u;
                }
            }
        }
    }
    __syncthreads();
    if (tid == 0) *cnt2 = lcnt;
}

// ------- T2->T1 frontier via CSR ranges (global bitmap dedupe) -------
__global__ __launch_bounds__(256) void frontier_csr(const int* __restrict__ list,
                                                    const int* __restrict__ cnt,
                                                    const int* __restrict__ ends,
                                                    const int* __restrict__ csr_src,
                                                    unsigned* __restrict__ bm_out,
                                                    int* __restrict__ out_list,
                                                    int* __restrict__ out_cnt) {
    int lane = threadIdx.x & 63;
    int wg = blockIdx.x * 4 + (threadIdx.x >> 6);
    int nW = gridDim.x * 4;
    int n = *cnt;
    for (int i = wg; i < n; i += nW) {
        int node = list[i];
        int end = ends[node];
        int beg = (node == 0) ? 0 : ends[node - 1];
        for (int e0 = beg; e0 < end; e0 += 64) {
            int u = 0;
            bool flag = false;
            if (e0 + lane < end) {
                u = csr_src[e0 + lane];
                unsigned old = atomicOr(&bm_out[u >> 5], 1u << (u & 31));
                flag = !((old >> (u & 31)) & 1);
            }
            unsigned long long mask = __ballot(flag);
            if (mask) {
                int leader = __ffsll((long long)mask) - 1;
                int base = 0;
                if (lane == leader) base = atomicAdd(out_cnt, __popcll(mask));
                base = __shfl(base, leader);
                if (flag) out_list[base + __popcll(mask & ((1ull << lane) - 1))] = u;
            }
        }
    }
}

// ------- W repack (blocks 0..23) + features fp32->bf16 pre-scaled (rest) -------
__global__ __launch_bounds__(256) void repack_convert(const float* __restrict__ Ws,
                                                      short* __restrict__ Wt,
                                                      const float* __restrict__ X,
                                                      const float* __restrict__ invout,
                                                      unsigned* __restrict__ Xs, int n2) {
    int bid = blockIdx.x;
    if (bid < 24) {
        int l = bid >> 3;
        int s = (bid & 7) * 256 + threadIdx.x;
        int lane = s & 63, ct = (s >> 6) & 7, k0 = s >> 9;
        int m = lane & 15, quad = lane >> 4;
        const float* W = Ws + (size_t)l * RANK * RANK;
        short* o = Wt + (size_t)l * 16384 + (size_t)s * 8;
#pragma unroll
        for (int j = 0; j < 8; j++)
            o[j] = (short)f2bf(W[(k0 * 32 + quad * 8 + j) * RANK + ct * 16 + m]);
    } else {
        int i = (bid - 24) * 256 + threadIdx.x;
        if (i < n2) {
            float s = invout[i >> 6];
            float2 v = ((const float2*)X)[i];
            Xs[i] = (unsigned)f2bf(v.x * s) | ((unsigned)f2bf(v.y * s) << 16);
        }
    }
}

// ---- fused layer: CSR gather (into LDS) + bf16 MFMA GEMM + invin/bias/LN/ReLU ----
// block = 16-node tile of list; 4 waves: gather 4 rows each, then 2 col-tiles each
template <int LAST>
__global__ __launch_bounds__(256) void layer_fused(const unsigned* __restrict__ Fin,
                                                   const int* __restrict__ ends,
                                                   const int* __restrict__ csr_src,
                                                   const short* __restrict__ Wt,
                                                   const float* __restrict__ invin,
                                                   const float* __restrict__ invout,
                                                   const float* __restrict__ bias,
                                                   const float* __restrict__ gamma,
                                                   const float* __restrict__ beta,
                                                   const int* __restrict__ list,
                                                   const int* __restrict__ cnt,
                                                   unsigned short* __restrict__ Fout,
                                                   float* __restrict__ out) {
    __shared__ short As[16][136];          // +8 pad: conflict-free frag reads
    __shared__ float sstat[2][4][16];      // [sum|sq][wave][row]
    __shared__ float sinv[2][16];          // [invin|invout][row]
    __shared__ int snode[16];
    int tid = threadIdx.x;
    int w = tid >> 6, lane = tid & 63;
    int seg = lane >> 4, m = lane & 15;    // seg doubles as MFMA 'quad'
    int n = *cnt;
    int tiles = (n + 15) >> 4;

    // per-lane column constants for the MFMA phase (cols (w*2+j)*16 + m)
    float bb[2], gg[2], pp[2];
#pragma unroll
    for (int j = 0; j < 2; j++) {
        int col = (w * 2 + j) * 16 + m;
        bb[j] = bias[col]; gg[j] = gamma[col]; pp[j] = beta[col];
    }

    for (int t = blockIdx.x; t < tiles; t += gridDim.x) {
        int base = t * 16;

        // ---- phase 1: gather 16 rows into LDS ----
        for (int q = 0; q < 4; q++) {
            int rr = w * 4 + q;
            int gr = base + rr;
            float ax[8];
#pragma unroll
            for (int k = 0; k < 8; k++) ax[k] = 0.f;
            int node = -1;
            if (gr < n) {
                node = list[gr];
                int end = ends[node];
                int e = (node == 0) ? 0 : ends[node - 1];
                while (e < end) {
                    int rem = end - e;
                    int myi = 0;
                    if (lane < rem) myi = csr_src[e + lane];
                    int nn = min(rem, 64);
                    int p = 0;
                    for (; p + 16 <= nn; p += 16) {
                        uint4 u[4];
#pragma unroll
                        for (int gi = 0; gi < 4; gi++) {
                            int idx = __shfl(myi, p + gi * 4 + seg);
                            u[gi] = *(const uint4*)(Fin + (size_t)idx * 64 + m * 4);
                        }
#pragma unroll
                        for (int gi = 0; gi < 4; gi++) {
                            ax[0] += __uint_as_float(u[gi].x << 16);
                            ax[1] += __uint_as_float(u[gi].x & 0xFFFF0000u);
                            ax[2] += __uint_as_float(u[gi].y << 16);
                            ax[3] += __uint_as_float(u[gi].y & 0xFFFF0000u);
                            ax[4] += __uint_as_float(u[gi].z << 16);
                            ax[5] += __uint_as_float(u[gi].z & 0xFFFF0000u);
                            ax[6] += __uint_as_float(u[gi].w << 16);
                            ax[7] += __uint_as_float(u[gi].w & 0xFFFF0000u);
                        }
                    }
                    for (; p < nn; p += 4) {
                        bool act = (p + seg) < nn;
                        int idx = __shfl(myi, (p + seg) & 63);
                        if (act) {
                            uint4 u = *(const uint4*)(Fin + (size_t)idx * 64 + m * 4);
                            ax[0] += __uint_as_float(u.x << 16);
                            ax[1] += __uint_as_float(u.x & 0xFFFF0000u);
                            ax[2] += __uint_as_float(u.y << 16);
                            ax[3] += __uint_as_float(u.y & 0xFFFF0000u);
                            ax[4] += __uint_as_float(u.z << 16);
                            ax[5] += __uint_as_float(u.z & 0xFFFF0000u);
                            ax[6] += __uint_as_float(u.w << 16);
                            ax[7] += __uint_as_float(u.w & 0xFFFF0000u);
                        }
                    }
                    e += nn;
                }
#pragma unroll
                for (int k = 0; k < 8; k++) {
                    ax[k] += __shfl_xor(ax[k], 16);
                    ax[k] += __shfl_xor(ax[k], 32);
                }
            }
            if (seg == 0) {   // lane m holds cols 8m..8m+7 of row rr
                uint4 o;
                o.x = (unsigned)f2bf(ax[0]) | ((unsigned)f2bf(ax[1]) << 16);
                o.y = (unsigned)f2bf(ax[2]) | ((unsigned)f2bf(ax[3]) << 16);
                o.z = (unsigned)f2bf(ax[4]) | ((unsigned)f2bf(ax[5]) << 16);
                o.w = (unsigned)f2bf(ax[6]) | ((unsigned)f2bf(ax[7]) << 16);
                *(uint4*)&As[rr][8 * m] = o;
            }
            if (lane == 0) {
                snode[rr] = node;
                sinv[0][rr] = (node >= 0) ? invin[node] : 1.f;
                sinv[1][rr] = (node >= 0) ? invout[node] : 1.f;
            }
        }
        __syncthreads();

        // ---- phase 2: MFMA (wave w covers cols w*32..w*32+31) ----
        short8 a[4];
#pragma unroll
        for (int k0 = 0; k0 < 4; k0++)
            a[k0] = *(const short8*)&As[m][k0 * 32 + seg * 8];
        v4f acc[2];
        acc[0] = (v4f){0.f, 0.f, 0.f, 0.f};
        acc[1] = (v4f){0.f, 0.f, 0.f, 0.f};
#pragma unroll
        for (int k0 = 0; k0 < 4; k0++) {
#pragma unroll
            for (int j = 0; j < 2; j++) {
                int ct = w * 2 + j;
                short8 b = *(const short8*)(Wt + (size_t)((k0 * 8 + ct) * 64 + lane) * 8);
                acc[j] = __builtin_amdgcn_mfma_f32_16x16x32_bf16(a[k0], b, acc[j], 0, 0, 0);
            }
        }

        // per-row partial LN stats over this wave's 32 cols
        float x[4][2];
#pragma unroll
        for (int r = 0; r < 4; r++) {
            int row = seg * 4 + r;
            float iv = sinv[0][row];
            float s = 0.f, sq = 0.f;
#pragma unroll
            for (int j = 0; j < 2; j++) {
                float c = acc[j][r] * iv + bb[j];
                x[r][j] = c;
                s += c; sq += c * c;
            }
#pragma unroll
            for (int off = 1; off < 16; off <<= 1) {
                s  += __shfl_xor(s, off);
                sq += __shfl_xor(sq, off);
            }
            if (m == 0) { sstat[0][w][row] = s; sstat[1][w][row] = sq; }
        }
        __syncthreads();

#pragma unroll
        for (int r = 0; r < 4; r++) {
            int row = seg * 4 + r;
            int gr = base + row;
            if (gr >= n) continue;
            float s  = sstat[0][0][row] + sstat[0][1][row] + sstat[0][2][row] + sstat[0][3][row];
            float sq = sstat[1][0][row] + sstat[1][1][row] + sstat[1][2][row] + sstat[1][3][row];
            float mu = s * (1.0f / RANK);
            float var = sq * (1.0f / RANK) - mu * mu;
            float rs = rsqrtf(var + LN_EPS);
#pragma unroll
            for (int j = 0; j < 2; j++) {
                int col = (w * 2 + j) * 16 + m;
                float y = fmaxf((x[r][j] - mu) * rs * gg[j] + pp[j], 0.f);
                if (LAST) {
                    out[(size_t)gr * RANK + col] = y;
                } else {
                    Fout[(size_t)snode[row] * RANK + col] = f2bf(y * sinv[1][row]);
                }
            }
        }
        __syncthreads();   // protect As/sstat before next tile
    }
}

extern "C" void kernel_launch(void* const* d_in, const int* in_sizes, int n_in,
                              void* d_out, int out_size, void* d_ws, size_t ws_size,
                              hipStream_t stream) {
    const float* features = (const float*)d_in[0];
    const int* src = (const int*)d_in[1];
    const int* dst = (const int*)d_in[2];
    const int* bnn = (const int*)d_in[3];
    const float* Ws = (const float*)d_in[4];
    const float* bs = (const float*)d_in[5];
    const float* gammas = (const float*)d_in[6];
    const float* betas = (const float*)d_in[7];
    float* out = (float*)d_out;

    int M  = in_sizes[0] / RANK;   // 50000
    int nE = in_sizes[1];          // 640000
    int nG = in_sizes[3];          // 50
    int bmw = (M + 31) / 32;

    char* ws = (char*)d_ws;
    size_t off = 0;
    auto alloc = [&](size_t bytes) {
        void* p = ws + off;
        off += (bytes + 255) & ~(size_t)255;
        return p;
    };
    int*   counts  = (int*)alloc((size_t)M * 4);
    int*   ends    = (int*)alloc((size_t)M * 4);
    int*   bsums   = (int*)alloc(256 * 4);
    float* invout  = (float*)alloc((size_t)M * 4);
    float* invin   = (float*)alloc((size_t)M * 4);
    int*   csr_src = (int*)alloc((size_t)nE * 4);
    short* Wt      = (short*)alloc((size_t)3 * 16384 * 2);
    short* Xs      = (short*)alloc((size_t)M * RANK * 2);
    short* F1      = (short*)alloc((size_t)M * RANK * 2);
    short* F2      = (short*)alloc((size_t)M * RANK * 2);
    int*   pdst    = (int*)alloc((size_t)ECH * BINS * 4);
    int*   psrc    = (int*)alloc((size_t)ECH * BINS * 4);
    char*  zbase   = (char*)alloc((size_t)(bmw + 1) * 4);   // bm1 + cnt1
    unsigned* bm1  = (unsigned*)zbase;
    int*   cnt1    = (int*)(bm1 + bmw);
    int*   cnt2    = (int*)alloc(256);
    int*   cnt3    = (int*)alloc(256);
    int*   T3      = (int*)alloc((size_t)((nG + 63) & ~63) * 4);
    int*   T2      = (int*)alloc((size_t)M * 4);
    int*   T1      = (int*)alloc((size_t)M * 4);

    int nb = (M + 255) / 256;   // 196 <= 256 (required by scan23_offs)

    hipMemsetAsync(zbase, 0, (size_t)(bmw + 1) * 4, stream);

    // ---- CSR build (4 kernels) ----
    hist_part<<<dim3(ECH, NCH, 2), BT, 0, stream>>>(src, dst, pdst, psrc, nE);
    reduce_scan1<<<nb, 256, 0, stream>>>(pdst, psrc, counts, invin, invout, ends, bsums, M);
    scan23_offs<<<nb, 256, 0, stream>>>(ends, counts, bsums, pdst, nb, M);
    fill_sorted<<<dim3(ECH, NCH), BT, 0, stream>>>(src, dst, pdst, csr_src, nE);

    // ---- frontiers (2 kernels) ----
    mark_expand3<<<1, 256, 0, stream>>>(bnn, nG, ends, csr_src, T3, cnt3, T2, cnt2);
    frontier_csr<<<64, 256, 0, stream>>>(T2, cnt2, ends, csr_src, bm1, T1, cnt1);

    // ---- weights + pre-scaled features (1 kernel) ----
    int cb = (M * 64 + 255) / 256;
    repack_convert<<<24 + cb, 256, 0, stream>>>(Ws, Wt, features, invout, (unsigned*)Xs, M * 64);

    // ---- fused layers (3 kernels) ----
    layer_fused<0><<<512, 256, 0, stream>>>((const unsigned*)Xs, ends, csr_src, Wt,
                                            invin, invout, bs, gammas, betas,
                                            T1, cnt1, (unsigned short*)F1, nullptr);
    layer_fused<0><<<64, 256, 0, stream>>>((const unsigned*)F1, ends, csr_src, Wt + 16384,
                                           invin, invout, bs + RANK, gammas + RANK, betas + RANK,
                                           T2, cnt2, (unsigned short*)F2, nullptr);
    layer_fused<1><<<(nG + 15) / 16, 256, 0, stream>>>((const unsigned*)F2, ends, csr_src, Wt + 32768,
                                                       invin, invout, bs + 2 * RANK,
                                                       gammas + 2 * RANK, betas + 2 * RANK,
                                                       T3, cnt3, nullptr, out);
}

// Round 10
// 178.148 us; speedup vs baseline: 1.5215x; 1.0744x over previous
//
#include <hip/hip_runtime.h>

#define RANK 128
#define LN_EPS 1e-5f

// CSR-build geometry (tuned for M=50000, nE=640000)
#define NCH 4
#define CHUNK 12800            // NCH*CHUNK = 51200 >= M ; LDS = 50 KB
#define BINS (NCH * CHUNK)
#define ECH 64                 // edge chunks
#define BT 1024                // threads per CSR-build block
#define BMWL ((BINS + 31) / 32) // LDS bitmap words (6.4 KB)

using short8 = __attribute__((ext_vector_type(8))) short;
using v4f    = __attribute__((ext_vector_type(4))) float;

__device__ inline unsigned short f2bf(float f) {
    unsigned u = __float_as_uint(f);
    unsigned r = (u + 0x7FFF + ((u >> 16) & 1)) >> 16;   // RNE
    return (unsigned short)r;
}

// ---- partial histograms (u16, no global atomics) + W repack on spare blocks ----
__global__ __launch_bounds__(BT) void hist_part(const int* __restrict__ src,
                                                const int* __restrict__ dst,
                                                unsigned short* __restrict__ pdst,
                                                unsigned short* __restrict__ psrc,
                                                const float* __restrict__ Ws,
                                                short* __restrict__ Wt, int nE) {
    int c = blockIdx.x, n = blockIdx.y, z = blockIdx.z;
    if (c == ECH) {   // repack blocks: (n,z) -> 8 blocks x 1024 threads
        int sid = (n + 4 * z) * BT + threadIdx.x;
        if (sid < 3 * 2048) {
            int l = sid >> 11;
            int s = sid & 2047;
            int lane = s & 63, ct = (s >> 6) & 7, k0 = s >> 9;
            int m = lane & 15, quad = lane >> 4;
            const float* W = Ws + (size_t)l * RANK * RANK;
            short* o = Wt + (size_t)l * 16384 + (size_t)s * 8;
#pragma unroll
            for (int j = 0; j < 8; j++)
                o[j] = (short)f2bf(W[(k0 * 32 + quad * 8 + j) * RANK + ct * 16 + m]);
        }
        return;
    }
    __shared__ int h[CHUNK];
    const int* arr = z ? src : dst;
    unsigned short* pout = z ? psrc : pdst;
    int base = n * CHUNK;
    for (int i = threadIdx.x; i < CHUNK; i += BT) h[i] = 0;
    __syncthreads();
    int epc = (nE + ECH - 1) / ECH;
    int e0 = c * epc, e1 = min(e0 + epc, nE);
    int tid = threadIdx.x;
    int a0 = min((e0 + 3) & ~3, e1);
    if (tid < a0 - e0) {
        int v = arr[e0 + tid] - base;
        if ((unsigned)v < (unsigned)CHUNK) atomicAdd(&h[v], 1);
    }
    int rem = e1 - a0;
    int nv = (rem > 0) ? (rem & ~3) : 0;
    for (int e = a0 + tid * 4; e < a0 + nv; e += BT * 4) {
        int4 v4 = *(const int4*)(arr + e);
        int v;
        v = v4.x - base; if ((unsigned)v < (unsigned)CHUNK) atomicAdd(&h[v], 1);
        v = v4.y - base; if ((unsigned)v < (unsigned)CHUNK) atomicAdd(&h[v], 1);
        v = v4.z - base; if ((unsigned)v < (unsigned)CHUNK) atomicAdd(&h[v], 1);
        v = v4.w - base; if ((unsigned)v < (unsigned)CHUNK) atomicAdd(&h[v], 1);
    }
    int t0 = a0 + nv;
    if (tid < e1 - t0) {
        int v = arr[t0 + tid] - base;
        if ((unsigned)v < (unsigned)CHUNK) atomicAdd(&h[v], 1);
    }
    __syncthreads();
    unsigned short* o = pout + (size_t)c * BINS + base;
    for (int i = threadIdx.x; i < CHUNK; i += BT) o[i] = (unsigned short)h[i];
}

// ------- reduce u16 partials -> counts/invin/invout + in-block inclusive scan -------
__global__ __launch_bounds__(256) void reduce_scan1(const unsigned short* __restrict__ pdst,
                                                    const unsigned short* __restrict__ psrc,
                                                    int* __restrict__ counts,
                                                    float* __restrict__ invin,
                                                    float* __restrict__ invout,
                                                    int* __restrict__ ends,
                                                    int* __restrict__ bsums, int M) {
    __shared__ int tmp[256];
    int tid = threadIdx.x;
    int gid = blockIdx.x * 256 + tid;
    int cd = 0, cs = 0;
    if (gid < M) {
#pragma unroll 8
        for (int c = 0; c < ECH; c++) {
            cd += pdst[(size_t)c * BINS + gid];
            cs += psrc[(size_t)c * BINS + gid];
        }
        counts[gid] = cd;
        invin[gid]  = rsqrtf(fmaxf((float)cd, 1.0f));
        invout[gid] = rsqrtf(fmaxf((float)cs, 1.0f));
    }
    tmp[tid] = cd;
    __syncthreads();
    for (int off = 1; off < 256; off <<= 1) {
        int t = (tid >= off) ? tmp[tid - off] : 0;
        __syncthreads();
        tmp[tid] += t;
        __syncthreads();
    }
    if (gid < M) ends[gid] = tmp[tid];
    if (tid == 255) bsums[blockIdx.x] = tmp[255];
}

// ------- global scan finish + per-(chunk,bin) int cursors -> pcur -------
__global__ __launch_bounds__(256) void scan23_offs(int* __restrict__ ends,
                                                   const int* __restrict__ counts,
                                                   const int* __restrict__ bsums,
                                                   const unsigned short* __restrict__ pdst,
                                                   int* __restrict__ pcur, int nb, int M) {
    __shared__ int red[256];
    int tid = threadIdx.x;
    int b = blockIdx.x;
    red[tid] = (tid < b && tid < nb) ? bsums[tid] : 0;   // nb <= 256
    __syncthreads();
    for (int off = 128; off > 0; off >>= 1) {
        if (tid < off) red[tid] += red[tid + off];
        __syncthreads();
    }
    int prefix = red[0];
    int gid = b * 256 + tid;
    if (gid < M) {
        int e = ends[gid] + prefix;   // inclusive global end
        ends[gid] = e;
        int run = e - counts[gid];    // exclusive start
#pragma unroll 8
        for (int c = 0; c < ECH; c++) {
            size_t idx = (size_t)c * BINS + gid;
            int t = pdst[idx];
            pcur[idx] = run;
            run += t;
        }
    }
}

// ---------------- CSR fill via LDS cursors (int4 edge loads) ----------------
__global__ __launch_bounds__(BT) void fill_sorted(const int* __restrict__ src,
                                                  const int* __restrict__ dst,
                                                  const int* __restrict__ pcur,
                                                  int* __restrict__ csr_src, int nE) {
    __shared__ int cur[CHUNK];
    int c = blockIdx.x, n = blockIdx.y;
    int base = n * CHUNK;
    const int* o = pcur + (size_t)c * BINS + base;
    for (int i = threadIdx.x; i < CHUNK; i += BT) cur[i] = o[i];
    __syncthreads();
    int epc = (nE + ECH - 1) / ECH;
    int e0 = c * epc, e1 = min(e0 + epc, nE);
    int tid = threadIdx.x;
    int a0 = min((e0 + 3) & ~3, e1);
    if (tid < a0 - e0) {
        int e = e0 + tid;
        int d = dst[e] - base;
        if ((unsigned)d < (unsigned)CHUNK) csr_src[atomicAdd(&cur[d], 1)] = src[e];
    }
    int rem = e1 - a0;
    int nv = (rem > 0) ? (rem & ~3) : 0;
    for (int e = a0 + tid * 4; e < a0 + nv; e += BT * 4) {
        int4 d4 = *(const int4*)(dst + e);
        int4 s4 = *(const int4*)(src + e);
        int d;
        d = d4.x - base; if ((unsigned)d < (unsigned)CHUNK) csr_src[atomicAdd(&cur[d], 1)] = s4.x;
        d = d4.y - base; if ((unsigned)d < (unsigned)CHUNK) csr_src[atomicAdd(&cur[d], 1)] = s4.y;
        d = d4.z - base; if ((unsigned)d < (unsigned)CHUNK) csr_src[atomicAdd(&cur[d], 1)] = s4.z;
        d = d4.w - base; if ((unsigned)d < (unsigned)CHUNK) csr_src[atomicAdd(&cur[d], 1)] = s4.w;
    }
    int t0 = a0 + nv;
    if (tid < e1 - t0) {
        int e = t0 + tid;
        int d = dst[e] - base;
        if ((unsigned)d < (unsigned)CHUNK) csr_src[atomicAdd(&cur[d], 1)] = src[e];
    }
}

// ------- T3 build + T3->T2 frontier in one single-block kernel (LDS bitmap) -------
__global__ __launch_bounds__(256) void mark_expand3(const int* __restrict__ bnn, int nG,
                                                    const int* __restrict__ ends,
                                                    const int* __restrict__ csr_src,
                                                    int* __restrict__ T3, int* __restrict__ cnt3,
                                                    int* __restrict__ T2, int* __restrict__ cnt2) {
    __shared__ unsigned bm[BMWL];
    __shared__ int lcnt;
    int tid = threadIdx.x;
    for (int i = tid; i < BMWL; i += 256) bm[i] = 0;
    if (tid == 0) lcnt = 0;
    __syncthreads();
    if (tid < 64) {
        int lane = tid;
        if (nG <= 64) {
            int v = (lane < nG) ? bnn[lane] : 0;
            int orig = v;
#pragma unroll
            for (int off = 1; off < 64; off <<= 1) {
                int t = __shfl_up(v, off);
                if (lane >= off) v += t;
            }
            int excl = v - orig;
            if (lane < nG) T3[lane] = excl;
            if (lane == 0) *cnt3 = nG;
        } else if (lane == 0) {
            int idx = 0;
            for (int g = 0; g < nG; g++) { T3[g] = idx; idx += bnn[g]; }
            *cnt3 = nG;
        }
    }
    __syncthreads();
    int lane = tid & 63, w = tid >> 6;
    for (int i = w; i < nG; i += 4) {
        int node = T3[i];
        int end = ends[node];
        int beg = (node == 0) ? 0 : ends[node - 1];
        for (int e0 = beg; e0 < end; e0 += 64) {
            if (e0 + lane < end) {
                int u = csr_src[e0 + lane];
                unsigned old = atomicOr(&bm[u >> 5], 1u << (u & 31));   // LDS
                if (!((old >> (u & 31)) & 1)) {
                    int pos = atomicAdd(&lcnt, 1);                      // LDS
                    T2[pos] = u;
                }
            }
        }
    }
    __syncthreads();
    if (tid == 0) *cnt2 = lcnt;
}

// ------- T2->T1 frontier via CSR ranges (global bitmap dedupe) -------
__global__ __launch_bounds__(256) void frontier_csr(const int* __restrict__ list,
                                                    const int* __restrict__ cnt,
                                                    const int* __restrict__ ends,
                                                    const int* __restrict__ csr_src,
                                                    unsigned* __restrict__ bm_out,
                                                    int* __restrict__ out_list,
                                                    int* __restrict__ out_cnt) {
    int lane = threadIdx.x & 63;
    int wg = blockIdx.x * 4 + (threadIdx.x >> 6);
    int nW = gridDim.x * 4;
    int n = *cnt;
    for (int i = wg; i < n; i += nW) {
        int node = list[i];
        int end = ends[node];
        int beg = (node == 0) ? 0 : ends[node - 1];
        for (int e0 = beg; e0 < end; e0 += 64) {
            int u = 0;
            bool flag = false;
            if (e0 + lane < end) {
                u = csr_src[e0 + lane];
                unsigned old = atomicOr(&bm_out[u >> 5], 1u << (u & 31));
                flag = !((old >> (u & 31)) & 1);
            }
            unsigned long long mask = __ballot(flag);
            if (mask) {
                int leader = __ffsll((long long)mask) - 1;
                int base = 0;
                if (lane == leader) base = atomicAdd(out_cnt, __popcll(mask));
                base = __shfl(base, leader);
                if (flag) out_list[base + __popcll(mask & ((1ull << lane) - 1))] = u;
            }
        }
    }
}

// ---- fused layer: CSR gather (LDS) + bf16 MFMA GEMM + invin/bias/LN/ReLU ----
// FP32IN: input rows are fp32 (features) scaled per-edge by edge_scale (invout)
template <int LAST, int FP32IN>
__global__ __launch_bounds__(256) void layer_fused(const void* __restrict__ FinV,
                                                   const float* __restrict__ edge_scale,
                                                   const int* __restrict__ ends,
                                                   const int* __restrict__ csr_src,
                                                   const short* __restrict__ Wt,
                                                   const float* __restrict__ invin,
                                                   const float* __restrict__ invout,
                                                   const float* __restrict__ bias,
                                                   const float* __restrict__ gamma,
                                                   const float* __restrict__ beta,
                                                   const int* __restrict__ list,
                                                   const int* __restrict__ cnt,
                                                   unsigned short* __restrict__ Fout,
                                                   float* __restrict__ out) {
    const unsigned* Fb = (const unsigned*)FinV;
    const float4*  Ff = (const float4*)FinV;
    __shared__ short As[16][136];
    __shared__ float sstat[2][4][16];
    __shared__ float sinv[2][16];
    __shared__ int snode[16];
    int tid = threadIdx.x;
    int w = tid >> 6, lane = tid & 63;
    int seg = lane >> 4, m = lane & 15;
    int n = *cnt;
    int tiles = (n + 15) >> 4;

    float bb[2], gg[2], pp[2];
#pragma unroll
    for (int j = 0; j < 2; j++) {
        int col = (w * 2 + j) * 16 + m;
        bb[j] = bias[col]; gg[j] = gamma[col]; pp[j] = beta[col];
    }

    for (int t = blockIdx.x; t < tiles; t += gridDim.x) {
        int base = t * 16;

        // ---- phase 1: gather 16 rows into LDS ----
        for (int q = 0; q < 4; q++) {
            int rr = w * 4 + q;
            int gr = base + rr;
            float ax[8];
#pragma unroll
            for (int k = 0; k < 8; k++) ax[k] = 0.f;
            int node = -1;
            if (gr < n) {
                node = list[gr];
                int end = ends[node];
                int e = (node == 0) ? 0 : ends[node - 1];
                while (e < end) {
                    int rem = end - e;
                    int myi = 0;
                    if (lane < rem) myi = csr_src[e + lane];
                    int nn = min(rem, 64);
                    int p = 0;
                    for (; p + 16 <= nn; p += 16) {
                        if (FP32IN) {
                            float4 fa[4], fb4[4]; float so[4];
#pragma unroll
                            for (int gi = 0; gi < 4; gi++) {
                                int idx = __shfl(myi, p + gi * 4 + seg);
                                so[gi] = edge_scale[idx];
                                const float4* qq = Ff + (size_t)idx * 32 + m * 2;
                                fa[gi] = qq[0]; fb4[gi] = qq[1];
                            }
#pragma unroll
                            for (int gi = 0; gi < 4; gi++) {
                                ax[0] += fa[gi].x * so[gi]; ax[1] += fa[gi].y * so[gi];
                                ax[2] += fa[gi].z * so[gi]; ax[3] += fa[gi].w * so[gi];
                                ax[4] += fb4[gi].x * so[gi]; ax[5] += fb4[gi].y * so[gi];
                                ax[6] += fb4[gi].z * so[gi]; ax[7] += fb4[gi].w * so[gi];
                            }
                        } else {
                            uint4 u[4];
#pragma unroll
                            for (int gi = 0; gi < 4; gi++) {
                                int idx = __shfl(myi, p + gi * 4 + seg);
                                u[gi] = *(const uint4*)(Fb + (size_t)idx * 64 + m * 4);
                            }
#pragma unroll
                            for (int gi = 0; gi < 4; gi++) {
                                ax[0] += __uint_as_float(u[gi].x << 16);
                                ax[1] += __uint_as_float(u[gi].x & 0xFFFF0000u);
                                ax[2] += __uint_as_float(u[gi].y << 16);
                                ax[3] += __uint_as_float(u[gi].y & 0xFFFF0000u);
                                ax[4] += __uint_as_float(u[gi].z << 16);
                                ax[5] += __uint_as_float(u[gi].z & 0xFFFF0000u);
                                ax[6] += __uint_as_float(u[gi].w << 16);
                                ax[7] += __uint_as_float(u[gi].w & 0xFFFF0000u);
                            }
                        }
                    }
                    for (; p < nn; p += 4) {
                        bool act = (p + seg) < nn;
                        int idx = __shfl(myi, (p + seg) & 63);
                        if (act) {
                            if (FP32IN) {
                                float so = edge_scale[idx];
                                const float4* qq = Ff + (size_t)idx * 32 + m * 2;
                                float4 fa = qq[0], fb4 = qq[1];
                                ax[0] += fa.x * so; ax[1] += fa.y * so;
                                ax[2] += fa.z * so; ax[3] += fa.w * so;
                                ax[4] += fb4.x * so; ax[5] += fb4.y * so;
                                ax[6] += fb4.z * so; ax[7] += fb4.w * so;
                            } else {
                                uint4 u = *(const uint4*)(Fb + (size_t)idx * 64 + m * 4);
                                ax[0] += __uint_as_float(u.x << 16);
                                ax[1] += __uint_as_float(u.x & 0xFFFF0000u);
                                ax[2] += __uint_as_float(u.y << 16);
                                ax[3] += __uint_as_float(u.y & 0xFFFF0000u);
                                ax[4] += __uint_as_float(u.z << 16);
                                ax[5] += __uint_as_float(u.z & 0xFFFF0000u);
                                ax[6] += __uint_as_float(u.w << 16);
                                ax[7] += __uint_as_float(u.w & 0xFFFF0000u);
                            }
                        }
                    }
                    e += nn;
                }
#pragma unroll
                for (int k = 0; k < 8; k++) {
                    ax[k] += __shfl_xor(ax[k], 16);
                    ax[k] += __shfl_xor(ax[k], 32);
                }
            }
            if (seg == 0) {   // lane m holds cols 8m..8m+7 of row rr
                uint4 o;
                o.x = (unsigned)f2bf(ax[0]) | ((unsigned)f2bf(ax[1]) << 16);
                o.y = (unsigned)f2bf(ax[2]) | ((unsigned)f2bf(ax[3]) << 16);
                o.z = (unsigned)f2bf(ax[4]) | ((unsigned)f2bf(ax[5]) << 16);
                o.w = (unsigned)f2bf(ax[6]) | ((unsigned)f2bf(ax[7]) << 16);
                *(uint4*)&As[rr][8 * m] = o;
            }
            if (lane == 0) {
                snode[rr] = node;
                sinv[0][rr] = (node >= 0) ? invin[node] : 1.f;
                sinv[1][rr] = (node >= 0) ? invout[node] : 1.f;
            }
        }
        __syncthreads();

        // ---- phase 2: MFMA (wave w covers cols w*32..w*32+31) ----
        short8 a[4];
#pragma unroll
        for (int k0 = 0; k0 < 4; k0++)
            a[k0] = *(const short8*)&As[m][k0 * 32 + seg * 8];
        v4f acc[2];
        acc[0] = (v4f){0.f, 0.f, 0.f, 0.f};
        acc[1] = (v4f){0.f, 0.f, 0.f, 0.f};
#pragma unroll
        for (int k0 = 0; k0 < 4; k0++) {
#pragma unroll
            for (int j = 0; j < 2; j++) {
                int ct = w * 2 + j;
                short8 b = *(const short8*)(Wt + (size_t)((k0 * 8 + ct) * 64 + lane) * 8);
                acc[j] = __builtin_amdgcn_mfma_f32_16x16x32_bf16(a[k0], b, acc[j], 0, 0, 0);
            }
        }

        float x[4][2];
#pragma unroll
        for (int r = 0; r < 4; r++) {
            int row = seg * 4 + r;
            float iv = sinv[0][row];
            float s = 0.f, sq = 0.f;
#pragma unroll
            for (int j = 0; j < 2; j++) {
                float c = acc[j][r] * iv + bb[j];
                x[r][j] = c;
                s += c; sq += c * c;
            }
#pragma unroll
            for (int off = 1; off < 16; off <<= 1) {
                s  += __shfl_xor(s, off);
                sq += __shfl_xor(sq, off);
            }
            if (m == 0) { sstat[0][w][row] = s; sstat[1][w][row] = sq; }
        }
        __syncthreads();

#pragma unroll
        for (int r = 0; r < 4; r++) {
            int row = seg * 4 + r;
            int gr = base + row;
            if (gr >= n) continue;
            float s  = sstat[0][0][row] + sstat[0][1][row] + sstat[0][2][row] + sstat[0][3][row];
            float sq = sstat[1][0][row] + sstat[1][1][row] + sstat[1][2][row] + sstat[1][3][row];
            float mu = s * (1.0f / RANK);
            float var = sq * (1.0f / RANK) - mu * mu;
            float rs = rsqrtf(var + LN_EPS);
#pragma unroll
            for (int j = 0; j < 2; j++) {
                int col = (w * 2 + j) * 16 + m;
                float y = fmaxf((x[r][j] - mu) * rs * gg[j] + pp[j], 0.f);
                if (LAST) {
                    out[(size_t)gr * RANK + col] = y;
                } else {
                    Fout[(size_t)snode[row] * RANK + col] = f2bf(y * sinv[1][row]);
                }
            }
        }
        __syncthreads();
    }
}

extern "C" void kernel_launch(void* const* d_in, const int* in_sizes, int n_in,
                              void* d_out, int out_size, void* d_ws, size_t ws_size,
                              hipStream_t stream) {
    const float* features = (const float*)d_in[0];
    const int* src = (const int*)d_in[1];
    const int* dst = (const int*)d_in[2];
    const int* bnn = (const int*)d_in[3];
    const float* Ws = (const float*)d_in[4];
    const float* bs = (const float*)d_in[5];
    const float* gammas = (const float*)d_in[6];
    const float* betas = (const float*)d_in[7];
    float* out = (float*)d_out;

    int M  = in_sizes[0] / RANK;   // 50000
    int nE = in_sizes[1];          // 640000
    int nG = in_sizes[3];          // 50
    int bmw = (M + 31) / 32;

    char* ws = (char*)d_ws;
    size_t off = 0;
    auto alloc = [&](size_t bytes) {
        void* p = ws + off;
        off += (bytes + 255) & ~(size_t)255;
        return p;
    };
    int*   counts  = (int*)alloc((size_t)M * 4);
    int*   ends    = (int*)alloc((size_t)M * 4);
    int*   bsums   = (int*)alloc(256 * 4);
    float* invout  = (float*)alloc((size_t)M * 4);
    float* invin   = (float*)alloc((size_t)M * 4);
    int*   csr_src = (int*)alloc((size_t)nE * 4);
    short* Wt      = (short*)alloc((size_t)3 * 16384 * 2);
    short* F1      = (short*)alloc((size_t)M * RANK * 2);
    short* F2      = (short*)alloc((size_t)M * RANK * 2);
    unsigned short* pdst = (unsigned short*)alloc((size_t)ECH * BINS * 2);  // 6.55 MB
    unsigned short* psrc = (unsigned short*)alloc((size_t)ECH * BINS * 2);  // 6.55 MB
    int*   pcur    = (int*)alloc((size_t)ECH * BINS * 4);                    // 13.1 MB
    char*  zbase   = (char*)alloc((size_t)(bmw + 1) * 4);   // bm1 + cnt1
    unsigned* bm1  = (unsigned*)zbase;
    int*   cnt1    = (int*)(bm1 + bmw);
    int*   cnt2    = (int*)alloc(256);
    int*   cnt3    = (int*)alloc(256);
    int*   T3      = (int*)alloc((size_t)((nG + 63) & ~63) * 4);
    int*   T2      = (int*)alloc((size_t)M * 4);
    int*   T1      = (int*)alloc((size_t)M * 4);

    int nb = (M + 255) / 256;   // 196 <= 256 (required by scan23_offs)

    hipMemsetAsync(zbase, 0, (size_t)(bmw + 1) * 4, stream);

    // ---- CSR build (4 kernels; hist also repacks W on spare blocks) ----
    hist_part<<<dim3(ECH + 1, NCH, 2), BT, 0, stream>>>(src, dst, pdst, psrc, Ws, Wt, nE);
    reduce_scan1<<<nb, 256, 0, stream>>>(pdst, psrc, counts, invin, invout, ends, bsums, M);
    scan23_offs<<<nb, 256, 0, stream>>>(ends, counts, bsums, pdst, pcur, nb, M);
    fill_sorted<<<dim3(ECH, NCH), BT, 0, stream>>>(src, dst, pcur, csr_src, nE);

    // ---- frontiers (2 kernels) ----
    mark_expand3<<<1, 256, 0, stream>>>(bnn, nG, ends, csr_src, T3, cnt3, T2, cnt2);
    frontier_csr<<<64, 256, 0, stream>>>(T2, cnt2, ends, csr_src, bm1, T1, cnt1);

    // ---- fused layers (3 kernels); L1 reads fp32 features w/ per-edge invout ----
    layer_fused<0, 1><<<512, 256, 0, stream>>>(features, invout, ends, csr_src, Wt,
                                               invin, invout, bs, gammas, betas,
                                               T1, cnt1, (unsigned short*)F1, nullptr);
    layer_fused<0, 0><<<64, 256, 0, stream>>>(F1, nullptr, ends, csr_src, Wt + 16384,
                                              invin, invout, bs + RANK, gammas + RANK, betas + RANK,
                                              T2, cnt2, (unsigned short*)F2, nullptr);
    layer_fused<1, 0><<<(nG + 15) / 16, 256, 0, stream>>>(F2, nullptr, ends, csr_src, Wt + 32768,
                                                          invin, invout, bs + 2 * RANK,
                                                          gammas + 2 * RANK, betas + 2 * RANK,
                                                          T3, cnt3, nullptr, out);
}